// Round 1
// baseline (2294.026 us; speedup 1.0000x reference)
//
#include <hip/hip_runtime.h>

#define NTOK 4096
#define HID 1024
#define QDIM 512
#define HEADS 4
#define NKEYS 128
#define TOPK 8
#define INTERDIM 4096

__device__ __forceinline__ float siluf(float x) { return x / (1.f + __expf(-x)); }

// C[M,N] = A[M,K] @ B[N,K]^T  (optionally fused dual-B: C = silu(A@B0^T) * (A@B1^T))
template<bool DUAL>
__global__ __launch_bounds__(256) void gemm_bt(
    const float* __restrict__ A, const float* __restrict__ B0,
    const float* __restrict__ B1, float* __restrict__ C,
    int M, int N, int K)
{
  __shared__ float As [16][65];
  __shared__ float Bs0[16][65];
  __shared__ float Bs1[16][65];
  const int tid = threadIdx.x;
  const int tx = tid & 15, ty = tid >> 4;
  const int m0 = blockIdx.y * 64, n0 = blockIdx.x * 64;
  float acc0[4][4] = {};
  float acc1[4][4] = {};
  for (int k0 = 0; k0 < K; k0 += 16) {
    const int c = tid & 15;
    const int rbase = tid >> 4;
#pragma unroll
    for (int it = 0; it < 4; ++it) {
      const int r = rbase + it * 16;
      As [c][r] = A [(long)(m0 + r) * K + k0 + c];
      Bs0[c][r] = B0[(long)(n0 + r) * K + k0 + c];
      if (DUAL) Bs1[c][r] = B1[(long)(n0 + r) * K + k0 + c];
    }
    __syncthreads();
#pragma unroll
    for (int kk = 0; kk < 16; ++kk) {
      float a[4], b0[4], b1[4];
#pragma unroll
      for (int i = 0; i < 4; ++i) a[i] = As[kk][ty * 4 + i];
#pragma unroll
      for (int j = 0; j < 4; ++j) b0[j] = Bs0[kk][tx * 4 + j];
      if (DUAL) {
#pragma unroll
        for (int j = 0; j < 4; ++j) b1[j] = Bs1[kk][tx * 4 + j];
      }
#pragma unroll
      for (int i = 0; i < 4; ++i)
#pragma unroll
        for (int j = 0; j < 4; ++j) {
          acc0[i][j] += a[i] * b0[j];
          if (DUAL) acc1[i][j] += a[i] * b1[j];
        }
    }
    __syncthreads();
  }
#pragma unroll
  for (int i = 0; i < 4; ++i) {
    const int m = m0 + ty * 4 + i;
#pragma unroll
    for (int j = 0; j < 4; ++j) {
      const int n = n0 + tx * 4 + j;
      const float v = DUAL ? siluf(acc0[i][j]) * acc1[i][j] : acc0[i][j];
      C[(long)m * N + n] = v;
    }
  }
}

// per (token, head): sim[2][128] -> top8 per p -> 64 combos -> top8 -> softmax
__global__ __launch_bounds__(128) void retrieval_kernel(
    const float* __restrict__ q,     // [NTOK, QDIM]
    const float* __restrict__ keys,  // [HEADS, NKEYS, 2, 64]
    int* __restrict__ out_idx,       // [NTOK, HEADS, TOPK]
    float* __restrict__ out_prob)    // [NTOK, HEADS, TOPK]
{
  const int token = blockIdx.x;
  const int h = blockIdx.y;
  const int k = threadIdx.x;  // 0..127 (one key per thread)
  __shared__ float qs[2][64];
  __shared__ float wv[2];
  __shared__ int   wi[2];
  __shared__ float stv[2][8];
  __shared__ int   sti[2][8];

  { const int p = k >> 6, n = k & 63;
    qs[p][n] = q[token * QDIM + p * 256 + h * 64 + n]; }
  __syncthreads();

  const float4* kr = (const float4*)(keys + ((long)(h * NKEYS + k) * 2) * 64);
  float s[2] = {0.f, 0.f};
#pragma unroll
  for (int p = 0; p < 2; ++p) {
#pragma unroll
    for (int n4 = 0; n4 < 16; ++n4) {
      const float4 kv = kr[p * 16 + n4];
      s[p] += qs[p][n4 * 4 + 0] * kv.x + qs[p][n4 * 4 + 1] * kv.y
            + qs[p][n4 * 4 + 2] * kv.z + qs[p][n4 * 4 + 3] * kv.w;
    }
  }

  // per-p top-8 extraction (descending), results in shared stv/sti
#pragma unroll
  for (int p = 0; p < 2; ++p) {
    float myv = s[p];
    for (int it = 0; it < 8; ++it) {
      float v = myv; int vi = k;
#pragma unroll
      for (int off = 32; off; off >>= 1) {
        const float ov = __shfl_xor(v, off);
        const int   oi = __shfl_xor(vi, off);
        if (ov > v || (ov == v && oi < vi)) { v = ov; vi = oi; }
      }
      if ((k & 63) == 0) { wv[k >> 6] = v; wi[k >> 6] = vi; }
      __syncthreads();
      float gv; int gi;
      if (wv[1] > wv[0] || (wv[1] == wv[0] && wi[1] < wi[0])) { gv = wv[1]; gi = wi[1]; }
      else { gv = wv[0]; gi = wi[0]; }
      if (k == 0) { stv[p][it] = gv; sti[p][it] = gi; }
      if (k == gi) myv = -3.4e38f;
      __syncthreads();
    }
  }

  // combine: 64 candidates live in wave 0 (one per lane)
  if (k < 64) {
    const int i = k >> 3, j = k & 7;
    float myc = stv[0][i] + stv[1][j];
    const int ci = sti[0][i] * NKEYS + sti[1][j];
    float mx = 0.f, sum = 0.f, myfv = 0.f;
    int myfi = 0;
    for (int it = 0; it < 8; ++it) {
      float v = myc; int vi = k;
#pragma unroll
      for (int off = 32; off; off >>= 1) {
        const float ov = __shfl_xor(v, off);
        const int   oi = __shfl_xor(vi, off);
        if (ov > v || (ov == v && oi < vi)) { v = ov; vi = oi; }
      }
      const int widx = __shfl(ci, vi);  // expert index of the winner lane
      if (it == 0) mx = v;              // extraction is descending -> first is max
      sum += __expf(v - mx);
      if (k == it) { myfv = v; myfi = widx; }
      if (k == vi) myc = -3.4e38f;
    }
    if (k < TOPK) {
      const int o = (token * HEADS + h) * TOPK + k;
      out_idx [o] = myfi;
      out_prob[o] = __expf(myfv - mx) / sum;
    }
  }
}

// per token: out[token,:] += sum_{e in 32} silu(hs . down[idx_e]) * prob_e * up[idx_e]
__global__ __launch_bounds__(256) void expert_kernel(
    const float* __restrict__ hs,
    const float* __restrict__ down_e,
    const float* __restrict__ up_e,
    const int* __restrict__ idx,
    const float* __restrict__ prob,
    float* __restrict__ out)
{
  const int token = blockIdx.x;
  const int t = threadIdx.x;
  __shared__ float red[4];
  const float4 h4 = ((const float4*)(hs + (long)token * HID))[t];
  float4 acc = make_float4(0.f, 0.f, 0.f, 0.f);
  for (int e = 0; e < HEADS * TOPK; ++e) {
    const int   ex = idx [token * 32 + e];
    const float p  = prob[token * 32 + e];
    const float4 d4 = ((const float4*)(down_e + (long)ex * HID))[t];
    float part = h4.x * d4.x + h4.y * d4.y + h4.z * d4.z + h4.w * d4.w;
#pragma unroll
    for (int off = 32; off; off >>= 1) part += __shfl_xor(part, off);
    if ((t & 63) == 0) red[t >> 6] = part;
    __syncthreads();
    const float wsum = red[0] + red[1] + red[2] + red[3];
    const float w = siluf(wsum) * p;
    const float4 u4 = ((const float4*)(up_e + (long)ex * HID))[t];
    acc.x += w * u4.x; acc.y += w * u4.y; acc.z += w * u4.z; acc.w += w * u4.w;
    __syncthreads();
  }
  float4* o = (float4*)(out + (long)token * HID);
  float4 cur = o[t];
  cur.x += acc.x; cur.y += acc.y; cur.z += acc.z; cur.w += acc.w;
  o[t] = cur;
}

extern "C" void kernel_launch(void* const* d_in, const int* in_sizes, int n_in,
                              void* d_out, int out_size, void* d_ws, size_t ws_size,
                              hipStream_t stream)
{
  const float* hs   = (const float*)d_in[0];
  const float* Wq   = (const float*)d_in[1];
  const float* keys = (const float*)d_in[2];
  const float* dwe  = (const float*)d_in[3];
  const float* upe  = (const float*)d_in[4];
  const float* Wg   = (const float*)d_in[5];
  const float* Wu   = (const float*)d_in[6];
  const float* Wd   = (const float*)d_in[7];
  float* out = (float*)d_out;

  float* qbuf  = (float*)d_ws;                            // 4096*512 f32   (8 MB)
  float* inter = qbuf + (size_t)NTOK * QDIM;              // 4096*4096 f32  (64 MB)
  int*   idxb  = (int*)(inter + (size_t)NTOK * INTERDIM); // 4096*32 i32
  float* probb = (float*)(idxb + NTOK * HEADS * TOPK);    // 4096*32 f32

  // 1) q = hs @ Wq^T
  gemm_bt<false><<<dim3(QDIM / 64, NTOK / 64), 256, 0, stream>>>(
      hs, Wq, nullptr, qbuf, NTOK, QDIM, HID);
  // 2) product-key retrieval -> (indices, softmax probs)
  retrieval_kernel<<<dim3(NTOK, HEADS), 128, 0, stream>>>(qbuf, keys, idxb, probb);
  // 3) inter = silu(hs @ Wg^T) * (hs @ Wu^T)
  gemm_bt<true><<<dim3(INTERDIM / 64, NTOK / 64), 256, 0, stream>>>(
      hs, Wg, Wu, inter, NTOK, INTERDIM, HID);
  // 4) out = inter @ Wd^T
  gemm_bt<false><<<dim3(HID / 64, NTOK / 64), 256, 0, stream>>>(
      inter, Wd, nullptr, out, NTOK, HID, INTERDIM);
  // 5) out += expert mixture
  expert_kernel<<<NTOK, 256, 0, stream>>>(hs, dwe, upe, idxb, probb, out);
}

// Round 2
// 746.011 us; speedup vs baseline: 3.0751x; 3.0751x over previous
//
#include <hip/hip_runtime.h>

#define NTOK 4096
#define HID 1024
#define QDIM 512
#define HEADS 4
#define NKEYS 128
#define TOPK 8
#define INTERDIM 4096

typedef __bf16 bf16x8 __attribute__((ext_vector_type(8)));
typedef __bf16 bf16x4 __attribute__((ext_vector_type(4)));
typedef float f32x4 __attribute__((ext_vector_type(4)));

__device__ __forceinline__ float siluf(float x) { return x / (1.f + __expf(-x)); }

#define GLD_LDS16(g, l)                                                                   \
  __builtin_amdgcn_global_load_lds(                                                      \
      (const __attribute__((address_space(1))) unsigned int*)(g),                        \
      (__attribute__((address_space(3))) unsigned int*)(l), 16, 0, 0)

// ---------------- fp32 -> bf16 cast ----------------
__global__ __launch_bounds__(256) void cast_bf16_kernel(const float* __restrict__ in,
                                                        __bf16* __restrict__ out, int n4)
{
  const int stride = gridDim.x * blockDim.x;
  for (int i = blockIdx.x * blockDim.x + threadIdx.x; i < n4; i += stride) {
    const float4 v = ((const float4*)in)[i];
    bf16x4 o;
    o[0] = (__bf16)v.x; o[1] = (__bf16)v.y; o[2] = (__bf16)v.z; o[3] = (__bf16)v.w;
    ((bf16x4*)out)[i] = o;
  }
}

// ---------------- bf16 MFMA GEMM: C[M,N] = A[M,K] @ B[N,K]^T ----------------
// m97 structure: 128x128 tile, BK=32, 4 waves (2x2), 4x4 fragments of 16x16x32,
// global_load_lds width-16 staging, single LDS buffer, 2 barriers per K-step.
// DUAL: C = silu(A@B0^T) * (A@B1^T). OUT_BF16: write bf16, else f32.
template<bool DUAL, bool OUT_BF16>
__global__ __launch_bounds__(256) void gemm_mfma(
    const __bf16* __restrict__ A, const __bf16* __restrict__ B0,
    const __bf16* __restrict__ B1, void* __restrict__ Cv,
    int M, int N, int K)
{
  __shared__ __attribute__((aligned(16))) __bf16 As [128 * 32];
  __shared__ __attribute__((aligned(16))) __bf16 Bs0[128 * 32];
  __shared__ __attribute__((aligned(16))) __bf16 Bs1[DUAL ? 128 * 32 : 8];

  const int tid  = threadIdx.x;
  const int wave = tid >> 6;
  const int lane = tid & 63;
  const int m0 = blockIdx.y * 128;
  const int n0 = blockIdx.x * 128;
  const int wr = wave >> 1, wc = wave & 1;
  const int lhi = lane >> 4, llo = lane & 15;

  f32x4 acc0[4][4] = {};
  f32x4 acc1[4][4] = {};

  // staging geometry: chunk c covers LDS bytes [c*16, c*16+16) = tile row c>>2, cols (c&3)*8..+8
  const int c0 = tid, c1 = 256 + tid;
  const int r0 = c0 >> 2, col0 = (c0 & 3) * 8;
  const int r1 = c1 >> 2, col1 = (c1 & 3) * 8;
  // wave-uniform LDS bases (HW adds lane*16)
  __bf16* ldsA0 = &As [(wave * 64) * 8];
  __bf16* ldsA1 = &As [(256 + wave * 64) * 8];
  __bf16* ldsB00 = &Bs0[(wave * 64) * 8];
  __bf16* ldsB01 = &Bs0[(256 + wave * 64) * 8];
  __bf16* ldsB10 = &Bs1[(wave * 64) * 8];
  __bf16* ldsB11 = &Bs1[(256 + wave * 64) * 8];

  for (int k0 = 0; k0 < K; k0 += 32) {
    GLD_LDS16(A  + (size_t)(m0 + r0) * K + k0 + col0, ldsA0);
    GLD_LDS16(A  + (size_t)(m0 + r1) * K + k0 + col1, ldsA1);
    GLD_LDS16(B0 + (size_t)(n0 + r0) * K + k0 + col0, ldsB00);
    GLD_LDS16(B0 + (size_t)(n0 + r1) * K + k0 + col1, ldsB01);
    if constexpr (DUAL) {
      GLD_LDS16(B1 + (size_t)(n0 + r0) * K + k0 + col0, ldsB10);
      GLD_LDS16(B1 + (size_t)(n0 + r1) * K + k0 + col1, ldsB11);
    }
    __syncthreads();  // compiler emits s_waitcnt vmcnt(0) before s_barrier

    bf16x8 afr[4], bfr0[4], bfr1[4];
#pragma unroll
    for (int mi = 0; mi < 4; ++mi)
      afr[mi] = *(const bf16x8*)&As[(wr * 64 + mi * 16 + llo) * 32 + lhi * 8];
#pragma unroll
    for (int nj = 0; nj < 4; ++nj)
      bfr0[nj] = *(const bf16x8*)&Bs0[(wc * 64 + nj * 16 + llo) * 32 + lhi * 8];
    if constexpr (DUAL) {
#pragma unroll
      for (int nj = 0; nj < 4; ++nj)
        bfr1[nj] = *(const bf16x8*)&Bs1[(wc * 64 + nj * 16 + llo) * 32 + lhi * 8];
    }
#pragma unroll
    for (int mi = 0; mi < 4; ++mi)
#pragma unroll
      for (int nj = 0; nj < 4; ++nj) {
        acc0[mi][nj] = __builtin_amdgcn_mfma_f32_16x16x32_bf16(afr[mi], bfr0[nj], acc0[mi][nj], 0, 0, 0);
        if constexpr (DUAL)
          acc1[mi][nj] = __builtin_amdgcn_mfma_f32_16x16x32_bf16(afr[mi], bfr1[nj], acc1[mi][nj], 0, 0, 0);
      }
    __syncthreads();
  }

#pragma unroll
  for (int mi = 0; mi < 4; ++mi)
#pragma unroll
    for (int nj = 0; nj < 4; ++nj)
#pragma unroll
      for (int r = 0; r < 4; ++r) {
        const int row = m0 + wr * 64 + mi * 16 + lhi * 4 + r;
        const int col = n0 + wc * 64 + nj * 16 + llo;
        float v = acc0[mi][nj][r];
        if constexpr (DUAL) v = siluf(v) * acc1[mi][nj][r];
        if constexpr (OUT_BF16) ((__bf16*)Cv)[(size_t)row * N + col] = (__bf16)v;
        else                    ((float*) Cv)[(size_t)row * N + col] = v;
      }
}

// ---------------- product-key retrieval ----------------
__global__ __launch_bounds__(128) void retrieval_kernel(
    const float* __restrict__ q,     // [NTOK, QDIM]
    const float* __restrict__ keys,  // [HEADS, NKEYS, 2, 64]
    int* __restrict__ out_idx,       // [NTOK, HEADS, TOPK]
    float* __restrict__ out_prob)    // [NTOK, HEADS, TOPK]
{
  const int token = blockIdx.x;
  const int h = blockIdx.y;
  const int k = threadIdx.x;  // 0..127 (one key per thread)
  __shared__ float qs[2][64];
  __shared__ float wv[2];
  __shared__ int   wi[2];
  __shared__ float stv[2][8];
  __shared__ int   sti[2][8];

  { const int p = k >> 6, n = k & 63;
    qs[p][n] = q[token * QDIM + p * 256 + h * 64 + n]; }
  __syncthreads();

  const float4* kr = (const float4*)(keys + ((long)(h * NKEYS + k) * 2) * 64);
  float s[2] = {0.f, 0.f};
#pragma unroll
  for (int p = 0; p < 2; ++p) {
#pragma unroll
    for (int n4 = 0; n4 < 16; ++n4) {
      const float4 kv = kr[p * 16 + n4];
      s[p] += qs[p][n4 * 4 + 0] * kv.x + qs[p][n4 * 4 + 1] * kv.y
            + qs[p][n4 * 4 + 2] * kv.z + qs[p][n4 * 4 + 3] * kv.w;
    }
  }

#pragma unroll
  for (int p = 0; p < 2; ++p) {
    float myv = s[p];
    for (int it = 0; it < 8; ++it) {
      float v = myv; int vi = k;
#pragma unroll
      for (int off = 32; off; off >>= 1) {
        const float ov = __shfl_xor(v, off);
        const int   oi = __shfl_xor(vi, off);
        if (ov > v || (ov == v && oi < vi)) { v = ov; vi = oi; }
      }
      if ((k & 63) == 0) { wv[k >> 6] = v; wi[k >> 6] = vi; }
      __syncthreads();
      float gv; int gi;
      if (wv[1] > wv[0] || (wv[1] == wv[0] && wi[1] < wi[0])) { gv = wv[1]; gi = wi[1]; }
      else { gv = wv[0]; gi = wi[0]; }
      if (k == 0) { stv[p][it] = gv; sti[p][it] = gi; }
      if (k == gi) myv = -3.4e38f;
      __syncthreads();
    }
  }

  if (k < 64) {
    const int i = k >> 3, j = k & 7;
    float myc = stv[0][i] + stv[1][j];
    const int ci = sti[0][i] * NKEYS + sti[1][j];
    float mx = 0.f, sum = 0.f, myfv = 0.f;
    int myfi = 0;
    for (int it = 0; it < 8; ++it) {
      float v = myc; int vi = k;
#pragma unroll
      for (int off = 32; off; off >>= 1) {
        const float ov = __shfl_xor(v, off);
        const int   oi = __shfl_xor(vi, off);
        if (ov > v || (ov == v && oi < vi)) { v = ov; vi = oi; }
      }
      const int widx = __shfl(ci, vi);
      if (it == 0) mx = v;
      sum += __expf(v - mx);
      if (k == it) { myfv = v; myfi = widx; }
      if (k == vi) myc = -3.4e38f;
    }
    if (k < TOPK) {
      const int o = (token * HEADS + h) * TOPK + k;
      out_idx [o] = myfi;
      out_prob[o] = __expf(myfv - mx) / sum;
    }
  }
}

// ---------------- expert mixture: out[token,:] += sum_e silu(hs.down_e)*prob_e*up_e ----------------
__global__ __launch_bounds__(256) void expert_kernel(
    const float* __restrict__ hs,
    const float* __restrict__ down_e,
    const float* __restrict__ up_e,
    const int* __restrict__ idx,
    const float* __restrict__ prob,
    float* __restrict__ out)
{
  const int token = blockIdx.x;
  const int t = threadIdx.x;
  __shared__ float red[4];
  const float4 h4 = ((const float4*)(hs + (long)token * HID))[t];
  float4 acc = make_float4(0.f, 0.f, 0.f, 0.f);
  for (int e = 0; e < HEADS * TOPK; ++e) {
    const int   ex = idx [token * 32 + e];
    const float p  = prob[token * 32 + e];
    const float4 d4 = ((const float4*)(down_e + (long)ex * HID))[t];
    float part = h4.x * d4.x + h4.y * d4.y + h4.z * d4.z + h4.w * d4.w;
#pragma unroll
    for (int off = 32; off; off >>= 1) part += __shfl_xor(part, off);
    if ((t & 63) == 0) red[t >> 6] = part;
    __syncthreads();
    const float wsum = red[0] + red[1] + red[2] + red[3];
    const float w = siluf(wsum) * p;
    const float4 u4 = ((const float4*)(up_e + (long)ex * HID))[t];
    acc.x += w * u4.x; acc.y += w * u4.y; acc.z += w * u4.z; acc.w += w * u4.w;
    __syncthreads();
  }
  float4* o = (float4*)(out + (long)token * HID);
  float4 cur = o[t];
  cur.x += acc.x; cur.y += acc.y; cur.z += acc.z; cur.w += acc.w;
  o[t] = cur;
}

extern "C" void kernel_launch(void* const* d_in, const int* in_sizes, int n_in,
                              void* d_out, int out_size, void* d_ws, size_t ws_size,
                              hipStream_t stream)
{
  const float* hs   = (const float*)d_in[0];
  const float* Wq   = (const float*)d_in[1];
  const float* keys = (const float*)d_in[2];
  const float* dwe  = (const float*)d_in[3];
  const float* upe  = (const float*)d_in[4];
  const float* Wg   = (const float*)d_in[5];
  const float* Wu   = (const float*)d_in[6];
  const float* Wd   = (const float*)d_in[7];
  float* out = (float*)d_out;

  // workspace layout (~77.5 MB)
  float*  qbuf    = (float*)d_ws;                       // 4096*512 f32
  int*    idxb    = (int*)(qbuf + (size_t)NTOK * QDIM);
  float*  probb   = (float*)(idxb + NTOK * HEADS * TOPK);
  __bf16* hs_bf   = (__bf16*)(probb + NTOK * HEADS * TOPK);
  __bf16* wq_bf   = hs_bf + (size_t)NTOK * HID;
  __bf16* wg_bf   = wq_bf + (size_t)QDIM * HID;
  __bf16* wu_bf   = wg_bf + (size_t)INTERDIM * HID;
  __bf16* wd_bf   = wu_bf + (size_t)INTERDIM * HID;
  __bf16* interbf = wd_bf + (size_t)HID * INTERDIM;     // 4096*4096 bf16

  // 1) casts
  cast_bf16_kernel<<<4096, 256, 0, stream>>>(hs, hs_bf, NTOK * HID / 4);
  cast_bf16_kernel<<<512,  256, 0, stream>>>(Wq, wq_bf, QDIM * HID / 4);
  cast_bf16_kernel<<<4096, 256, 0, stream>>>(Wg, wg_bf, INTERDIM * HID / 4);
  cast_bf16_kernel<<<4096, 256, 0, stream>>>(Wu, wu_bf, INTERDIM * HID / 4);
  cast_bf16_kernel<<<4096, 256, 0, stream>>>(Wd, wd_bf, HID * INTERDIM / 4);

  // 2) q = hs @ Wq^T   (f32 out for retrieval)
  gemm_mfma<false, false><<<dim3(QDIM / 128, NTOK / 128), 256, 0, stream>>>(
      hs_bf, wq_bf, nullptr, qbuf, NTOK, QDIM, HID);

  // 3) retrieval -> (indices, probs)
  retrieval_kernel<<<dim3(NTOK, HEADS), 128, 0, stream>>>(qbuf, keys, idxb, probb);

  // 4) inter = silu(hs @ Wg^T) * (hs @ Wu^T)  (bf16 out)
  gemm_mfma<true, true><<<dim3(INTERDIM / 128, NTOK / 128), 256, 0, stream>>>(
      hs_bf, wg_bf, wu_bf, interbf, NTOK, INTERDIM, HID);

  // 5) out = inter @ Wd^T  (f32 out)
  gemm_mfma<false, false><<<dim3(HID / 128, NTOK / 128), 256, 0, stream>>>(
      interbf, wd_bf, nullptr, out, NTOK, HID, INTERDIM);

  // 6) out += expert mixture
  expert_kernel<<<NTOK, 256, 0, stream>>>(hs, dwe, upe, idxb, probb, out);
}

// Round 3
// 640.549 us; speedup vs baseline: 3.5813x; 1.1646x over previous
//
#include <hip/hip_runtime.h>

#define NTOK 4096
#define HID 1024
#define QDIM 512
#define HEADS 4
#define NKEYS 128
#define TOPK 8
#define INTERDIM 4096

typedef __bf16 bf16x8 __attribute__((ext_vector_type(8)));
typedef __bf16 bf16x4 __attribute__((ext_vector_type(4)));
typedef float f32x4 __attribute__((ext_vector_type(4)));

__device__ __forceinline__ float siluf(float x) { return x / (1.f + __expf(-x)); }
__device__ __forceinline__ float dot4(float4 a, float4 b) {
  return a.x * b.x + a.y * b.y + a.z * b.z + a.w * b.w;
}

#define GLD_LDS16(g, l)                                                                   \
  __builtin_amdgcn_global_load_lds(                                                      \
      (const __attribute__((address_space(1))) unsigned int*)(g),                        \
      (__attribute__((address_space(3))) unsigned int*)(l), 16, 0, 0)

// ---------------- fp32 -> bf16 cast ----------------
__global__ __launch_bounds__(256) void cast_bf16_kernel(const float* __restrict__ in,
                                                        __bf16* __restrict__ out, int n4)
{
  const int stride = gridDim.x * blockDim.x;
  for (int i = blockIdx.x * blockDim.x + threadIdx.x; i < n4; i += stride) {
    const float4 v = ((const float4*)in)[i];
    bf16x4 o;
    o[0] = (__bf16)v.x; o[1] = (__bf16)v.y; o[2] = (__bf16)v.z; o[3] = (__bf16)v.w;
    ((bf16x4*)out)[i] = o;
  }
}

// ---------------- bf16 MFMA GEMM: C[M,N] = A[M,K] @ B[N,K]^T ----------------
template<bool DUAL, bool OUT_BF16>
__global__ __launch_bounds__(256) void gemm_mfma(
    const __bf16* __restrict__ A, const __bf16* __restrict__ B0,
    const __bf16* __restrict__ B1, void* __restrict__ Cv,
    int M, int N, int K)
{
  __shared__ __attribute__((aligned(16))) __bf16 As [128 * 32];
  __shared__ __attribute__((aligned(16))) __bf16 Bs0[128 * 32];
  __shared__ __attribute__((aligned(16))) __bf16 Bs1[DUAL ? 128 * 32 : 8];

  const int tid  = threadIdx.x;
  const int wave = tid >> 6;
  const int lane = tid & 63;
  const int m0 = blockIdx.y * 128;
  const int n0 = blockIdx.x * 128;
  const int wr = wave >> 1, wc = wave & 1;
  const int lhi = lane >> 4, llo = lane & 15;

  f32x4 acc0[4][4] = {};
  f32x4 acc1[4][4] = {};

  const int c0 = tid, c1 = 256 + tid;
  const int r0 = c0 >> 2, col0 = (c0 & 3) * 8;
  const int r1 = c1 >> 2, col1 = (c1 & 3) * 8;
  __bf16* ldsA0 = &As [(wave * 64) * 8];
  __bf16* ldsA1 = &As [(256 + wave * 64) * 8];
  __bf16* ldsB00 = &Bs0[(wave * 64) * 8];
  __bf16* ldsB01 = &Bs0[(256 + wave * 64) * 8];
  __bf16* ldsB10 = &Bs1[(wave * 64) * 8];
  __bf16* ldsB11 = &Bs1[(256 + wave * 64) * 8];

  for (int k0 = 0; k0 < K; k0 += 32) {
    GLD_LDS16(A  + (size_t)(m0 + r0) * K + k0 + col0, ldsA0);
    GLD_LDS16(A  + (size_t)(m0 + r1) * K + k0 + col1, ldsA1);
    GLD_LDS16(B0 + (size_t)(n0 + r0) * K + k0 + col0, ldsB00);
    GLD_LDS16(B0 + (size_t)(n0 + r1) * K + k0 + col1, ldsB01);
    if constexpr (DUAL) {
      GLD_LDS16(B1 + (size_t)(n0 + r0) * K + k0 + col0, ldsB10);
      GLD_LDS16(B1 + (size_t)(n0 + r1) * K + k0 + col1, ldsB11);
    }
    __syncthreads();

    bf16x8 afr[4], bfr0[4], bfr1[4];
#pragma unroll
    for (int mi = 0; mi < 4; ++mi)
      afr[mi] = *(const bf16x8*)&As[(wr * 64 + mi * 16 + llo) * 32 + lhi * 8];
#pragma unroll
    for (int nj = 0; nj < 4; ++nj)
      bfr0[nj] = *(const bf16x8*)&Bs0[(wc * 64 + nj * 16 + llo) * 32 + lhi * 8];
    if constexpr (DUAL) {
#pragma unroll
      for (int nj = 0; nj < 4; ++nj)
        bfr1[nj] = *(const bf16x8*)&Bs1[(wc * 64 + nj * 16 + llo) * 32 + lhi * 8];
    }
#pragma unroll
    for (int mi = 0; mi < 4; ++mi)
#pragma unroll
      for (int nj = 0; nj < 4; ++nj) {
        acc0[mi][nj] = __builtin_amdgcn_mfma_f32_16x16x32_bf16(afr[mi], bfr0[nj], acc0[mi][nj], 0, 0, 0);
        if constexpr (DUAL)
          acc1[mi][nj] = __builtin_amdgcn_mfma_f32_16x16x32_bf16(afr[mi], bfr1[nj], acc1[mi][nj], 0, 0, 0);
      }
    __syncthreads();
  }

#pragma unroll
  for (int mi = 0; mi < 4; ++mi)
#pragma unroll
    for (int nj = 0; nj < 4; ++nj)
#pragma unroll
      for (int r = 0; r < 4; ++r) {
        const int row = m0 + wr * 64 + mi * 16 + lhi * 4 + r;
        const int col = n0 + wc * 64 + nj * 16 + llo;
        float v = acc0[mi][nj][r];
        if constexpr (DUAL) v = siluf(v) * acc1[mi][nj][r];
        if constexpr (OUT_BF16) ((__bf16*)Cv)[(size_t)row * N + col] = (__bf16)v;
        else                    ((float*) Cv)[(size_t)row * N + col] = v;
      }
}

// ---------------- product-key retrieval: one WAVE per (token, head) ----------------
// lane owns keys l and l+64; per-p top-8 by iterative wave-argmax (no barriers);
// 64 combos (one per lane) -> top-8 -> softmax. Tie-break: lower index (matches lax.top_k).
__device__ __forceinline__ void top8_pair(float v0, float v1, int lane, int sel,
                                          float& cv, int& cidx)
{
  const int i0 = lane, i1 = lane + 64;
#pragma unroll 1
  for (int it = 0; it < 8; ++it) {
    float mv; int mi;
    if (v1 > v0) { mv = v1; mi = i1; } else { mv = v0; mi = i0; }
#pragma unroll
    for (int off = 32; off; off >>= 1) {
      const float ov = __shfl_xor(mv, off);
      const int   oi = __shfl_xor(mi, off);
      if (ov > mv || (ov == mv && oi < mi)) { mv = ov; mi = oi; }
    }
    if (sel == it) { cv = mv; cidx = mi; }
    if (mi == i0) v0 = -3.4e38f;
    if (mi == i1) v1 = -3.4e38f;
  }
}

__global__ __launch_bounds__(256) void retrieval_kernel(
    const float* __restrict__ q,     // [NTOK, QDIM]
    const float* __restrict__ keys,  // [HEADS, NKEYS, 2, 64]
    int* __restrict__ out_idx,       // [NTOK, HEADS, TOPK]
    float* __restrict__ out_prob)    // [NTOK, HEADS, TOPK]
{
  const int token = blockIdx.x;
  const int t = threadIdx.x;
  const int w = t >> 6;       // head
  const int l = t & 63;
  __shared__ float qs[HEADS][2][64];

  // stage q: wave w loads its head's two 64-float slices (coalesced)
  qs[w][0][l] = q[(size_t)token * QDIM + 0 * 256 + w * 64 + l];
  qs[w][1][l] = q[(size_t)token * QDIM + 1 * 256 + w * 64 + l];
  __syncthreads();

  // dot: keys l and l+64, both p
  const float* kb = keys + ((size_t)(w * NKEYS + l) * 2) * 64;
  const float4* K00 = (const float4*)kb;            // key l,    p=0
  const float4* K01 = (const float4*)(kb + 64);     // key l,    p=1
  const float4* K10 = (const float4*)(kb + 64 * 128);     // key l+64, p=0
  const float4* K11 = (const float4*)(kb + 64 * 128 + 64);
  float s00 = 0.f, s01 = 0.f, s10 = 0.f, s11 = 0.f;
#pragma unroll
  for (int n4 = 0; n4 < 16; ++n4) {
    const float4 q0 = *(const float4*)&qs[w][0][n4 * 4];
    const float4 q1 = *(const float4*)&qs[w][1][n4 * 4];
    s00 += dot4(q0, K00[n4]);
    s01 += dot4(q1, K01[n4]);
    s10 += dot4(q0, K10[n4]);
    s11 += dot4(q1, K11[n4]);
  }

  // per-p top-8; lane l keeps combo candidate (cx: slot l>>3 of p0, cy: slot l&7 of p1)
  float cx, cy; int cix, ciy;
  top8_pair(s00, s10, l, l >> 3, cx, cix);
  top8_pair(s01, s11, l, l & 7,  cy, ciy);

  // combine + top-8 + softmax (candidate position l matches lax.top_k flatten order)
  float cand = cx + cy;
  const int cid = cix * NKEYS + ciy;
  float mx = 0.f, sum = 0.f, myfv = 0.f;
  int myfi = 0;
#pragma unroll 1
  for (int it = 0; it < 8; ++it) {
    float v = cand; int vi = l;
#pragma unroll
    for (int off = 32; off; off >>= 1) {
      const float ov = __shfl_xor(v, off);
      const int   oi = __shfl_xor(vi, off);
      if (ov > v || (ov == v && oi < vi)) { v = ov; vi = oi; }
    }
    const int widx = __shfl(cid, vi);
    if (it == 0) mx = v;
    sum += __expf(v - mx);
    if (l == it) { myfv = v; myfi = widx; }
    if (l == vi) cand = -3.4e38f;
  }
  if (l < TOPK) {
    const int o = (token * HEADS + w) * TOPK + l;
    out_idx [o] = myfi;
    out_prob[o] = __expf(myfv - mx) / sum;
  }
}

// ---------------- expert mixture: 4 waves x 8 experts, barrier-free inner loop ----------------
__global__ __launch_bounds__(256) void expert_kernel(
    const float* __restrict__ hs,
    const float* __restrict__ down_e,
    const float* __restrict__ up_e,
    const int* __restrict__ idx,
    const float* __restrict__ prob,
    float* __restrict__ out)
{
  const int token = blockIdx.x;
  const int t = threadIdx.x, w = t >> 6, l = t & 63;
  __shared__ float4 sred[4][256];

  const float4* hrow = (const float4*)(hs + (size_t)token * HID);
  const float4 h0 = hrow[l], h1 = hrow[64 + l], h2 = hrow[128 + l], h3 = hrow[192 + l];
  float4 a0 = {0,0,0,0}, a1 = {0,0,0,0}, a2 = {0,0,0,0}, a3 = {0,0,0,0};

  const int*   tidx  = idx  + token * 32 + w * 8;
  const float* tprob = prob + token * 32 + w * 8;
#pragma unroll 2
  for (int e = 0; e < 8; ++e) {
    const int   ex = tidx[e];
    const float p  = tprob[e];
    const float4* drow = (const float4*)(down_e + (size_t)ex * HID);
    const float4 d0 = drow[l], d1 = drow[64 + l], d2 = drow[128 + l], d3 = drow[192 + l];
    float part = dot4(h0, d0) + dot4(h1, d1) + dot4(h2, d2) + dot4(h3, d3);
#pragma unroll
    for (int off = 32; off; off >>= 1) part += __shfl_xor(part, off);
    const float wgt = siluf(part) * p;
    const float4* urow = (const float4*)(up_e + (size_t)ex * HID);
    const float4 u0 = urow[l], u1 = urow[64 + l], u2 = urow[128 + l], u3 = urow[192 + l];
    a0.x += wgt * u0.x; a0.y += wgt * u0.y; a0.z += wgt * u0.z; a0.w += wgt * u0.w;
    a1.x += wgt * u1.x; a1.y += wgt * u1.y; a1.z += wgt * u1.z; a1.w += wgt * u1.w;
    a2.x += wgt * u2.x; a2.y += wgt * u2.y; a2.z += wgt * u2.z; a2.w += wgt * u2.w;
    a3.x += wgt * u3.x; a3.y += wgt * u3.y; a3.z += wgt * u3.z; a3.w += wgt * u3.w;
  }
  sred[w][l] = a0; sred[w][64 + l] = a1; sred[w][128 + l] = a2; sred[w][192 + l] = a3;
  __syncthreads();

  const float4 r0 = sred[0][t], r1 = sred[1][t], r2 = sred[2][t], r3 = sred[3][t];
  float4* o = (float4*)(out + (size_t)token * HID);
  float4 cur = o[t];
  cur.x += r0.x + r1.x + r2.x + r3.x;
  cur.y += r0.y + r1.y + r2.y + r3.y;
  cur.z += r0.z + r1.z + r2.z + r3.z;
  cur.w += r0.w + r1.w + r2.w + r3.w;
  o[t] = cur;
}

extern "C" void kernel_launch(void* const* d_in, const int* in_sizes, int n_in,
                              void* d_out, int out_size, void* d_ws, size_t ws_size,
                              hipStream_t stream)
{
  const float* hs   = (const float*)d_in[0];
  const float* Wq   = (const float*)d_in[1];
  const float* keys = (const float*)d_in[2];
  const float* dwe  = (const float*)d_in[3];
  const float* upe  = (const float*)d_in[4];
  const float* Wg   = (const float*)d_in[5];
  const float* Wu   = (const float*)d_in[6];
  const float* Wd   = (const float*)d_in[7];
  float* out = (float*)d_out;

  float*  qbuf    = (float*)d_ws;
  int*    idxb    = (int*)(qbuf + (size_t)NTOK * QDIM);
  float*  probb   = (float*)(idxb + NTOK * HEADS * TOPK);
  __bf16* hs_bf   = (__bf16*)(probb + NTOK * HEADS * TOPK);
  __bf16* wq_bf   = hs_bf + (size_t)NTOK * HID;
  __bf16* wg_bf   = wq_bf + (size_t)QDIM * HID;
  __bf16* wu_bf   = wg_bf + (size_t)INTERDIM * HID;
  __bf16* wd_bf   = wu_bf + (size_t)INTERDIM * HID;
  __bf16* interbf = wd_bf + (size_t)HID * INTERDIM;

  cast_bf16_kernel<<<4096, 256, 0, stream>>>(hs, hs_bf, NTOK * HID / 4);
  cast_bf16_kernel<<<512,  256, 0, stream>>>(Wq, wq_bf, QDIM * HID / 4);
  cast_bf16_kernel<<<4096, 256, 0, stream>>>(Wg, wg_bf, INTERDIM * HID / 4);
  cast_bf16_kernel<<<4096, 256, 0, stream>>>(Wu, wu_bf, INTERDIM * HID / 4);
  cast_bf16_kernel<<<4096, 256, 0, stream>>>(Wd, wd_bf, HID * INTERDIM / 4);

  gemm_mfma<false, false><<<dim3(QDIM / 128, NTOK / 128), 256, 0, stream>>>(
      hs_bf, wq_bf, nullptr, qbuf, NTOK, QDIM, HID);

  retrieval_kernel<<<NTOK, 256, 0, stream>>>(qbuf, keys, idxb, probb);

  gemm_mfma<true, true><<<dim3(INTERDIM / 128, NTOK / 128), 256, 0, stream>>>(
      hs_bf, wg_bf, wu_bf, interbf, NTOK, INTERDIM, HID);

  gemm_mfma<false, false><<<dim3(HID / 128, NTOK / 128), 256, 0, stream>>>(
      interbf, wd_bf, nullptr, out, NTOK, HID, INTERDIM);

  expert_kernel<<<NTOK, 256, 0, stream>>>(hs, dwe, upe, idxb, probb, out);
}

// Round 4
// 629.575 us; speedup vs baseline: 3.6438x; 1.0174x over previous
//
#include <hip/hip_runtime.h>

#define NTOK 4096
#define HID 1024
#define QDIM 512
#define HEADS 4
#define NKEYS 128
#define TOPK 8
#define INTERDIM 4096

typedef __bf16 bf16x8 __attribute__((ext_vector_type(8)));
typedef __bf16 bf16x4 __attribute__((ext_vector_type(4)));
typedef float f32x4 __attribute__((ext_vector_type(4)));

__device__ __forceinline__ float siluf(float x) { return x / (1.f + __expf(-x)); }
__device__ __forceinline__ float dot4(float4 a, float4 b) {
  return a.x * b.x + a.y * b.y + a.z * b.z + a.w * b.w;
}

#define GLD_LDS16(g, l)                                                                   \
  __builtin_amdgcn_global_load_lds(                                                      \
      (const __attribute__((address_space(1))) unsigned int*)(g),                        \
      (__attribute__((address_space(3))) unsigned int*)(l), 16, 0, 0)

// ---------------- fp32 -> bf16 cast ----------------
__global__ __launch_bounds__(256) void cast_bf16_kernel(const float* __restrict__ in,
                                                        __bf16* __restrict__ out, int n4)
{
  const int stride = gridDim.x * blockDim.x;
  for (int i = blockIdx.x * blockDim.x + threadIdx.x; i < n4; i += stride) {
    const float4 v = ((const float4*)in)[i];
    bf16x4 o;
    o[0] = (__bf16)v.x; o[1] = (__bf16)v.y; o[2] = (__bf16)v.z; o[3] = (__bf16)v.w;
    ((bf16x4*)out)[i] = o;
  }
}

// ---------------- bf16 MFMA GEMM: C[M,N] = A[M,K] @ B[N,K]^T ----------------
template<bool DUAL, bool OUT_BF16>
__global__ __launch_bounds__(256) void gemm_mfma(
    const __bf16* __restrict__ A, const __bf16* __restrict__ B0,
    const __bf16* __restrict__ B1, void* __restrict__ Cv,
    int M, int N, int K)
{
  __shared__ __attribute__((aligned(16))) __bf16 As [128 * 32];
  __shared__ __attribute__((aligned(16))) __bf16 Bs0[128 * 32];
  __shared__ __attribute__((aligned(16))) __bf16 Bs1[DUAL ? 128 * 32 : 8];

  const int tid  = threadIdx.x;
  const int wave = tid >> 6;
  const int lane = tid & 63;
  const int m0 = blockIdx.y * 128;
  const int n0 = blockIdx.x * 128;
  const int wr = wave >> 1, wc = wave & 1;
  const int lhi = lane >> 4, llo = lane & 15;

  f32x4 acc0[4][4] = {};
  f32x4 acc1[4][4] = {};

  const int c0 = tid, c1 = 256 + tid;
  const int r0 = c0 >> 2, col0 = (c0 & 3) * 8;
  const int r1 = c1 >> 2, col1 = (c1 & 3) * 8;
  __bf16* ldsA0 = &As [(wave * 64) * 8];
  __bf16* ldsA1 = &As [(256 + wave * 64) * 8];
  __bf16* ldsB00 = &Bs0[(wave * 64) * 8];
  __bf16* ldsB01 = &Bs0[(256 + wave * 64) * 8];
  __bf16* ldsB10 = &Bs1[(wave * 64) * 8];
  __bf16* ldsB11 = &Bs1[(256 + wave * 64) * 8];

  for (int k0 = 0; k0 < K; k0 += 32) {
    GLD_LDS16(A  + (size_t)(m0 + r0) * K + k0 + col0, ldsA0);
    GLD_LDS16(A  + (size_t)(m0 + r1) * K + k0 + col1, ldsA1);
    GLD_LDS16(B0 + (size_t)(n0 + r0) * K + k0 + col0, ldsB00);
    GLD_LDS16(B0 + (size_t)(n0 + r1) * K + k0 + col1, ldsB01);
    if constexpr (DUAL) {
      GLD_LDS16(B1 + (size_t)(n0 + r0) * K + k0 + col0, ldsB10);
      GLD_LDS16(B1 + (size_t)(n0 + r1) * K + k0 + col1, ldsB11);
    }
    __syncthreads();

    bf16x8 afr[4], bfr0[4], bfr1[4];
#pragma unroll
    for (int mi = 0; mi < 4; ++mi)
      afr[mi] = *(const bf16x8*)&As[(wr * 64 + mi * 16 + llo) * 32 + lhi * 8];
#pragma unroll
    for (int nj = 0; nj < 4; ++nj)
      bfr0[nj] = *(const bf16x8*)&Bs0[(wc * 64 + nj * 16 + llo) * 32 + lhi * 8];
    if constexpr (DUAL) {
#pragma unroll
      for (int nj = 0; nj < 4; ++nj)
        bfr1[nj] = *(const bf16x8*)&Bs1[(wc * 64 + nj * 16 + llo) * 32 + lhi * 8];
    }
#pragma unroll
    for (int mi = 0; mi < 4; ++mi)
#pragma unroll
      for (int nj = 0; nj < 4; ++nj) {
        acc0[mi][nj] = __builtin_amdgcn_mfma_f32_16x16x32_bf16(afr[mi], bfr0[nj], acc0[mi][nj], 0, 0, 0);
        if constexpr (DUAL)
          acc1[mi][nj] = __builtin_amdgcn_mfma_f32_16x16x32_bf16(afr[mi], bfr1[nj], acc1[mi][nj], 0, 0, 0);
      }
    __syncthreads();
  }

#pragma unroll
  for (int mi = 0; mi < 4; ++mi)
#pragma unroll
    for (int nj = 0; nj < 4; ++nj)
#pragma unroll
      for (int r = 0; r < 4; ++r) {
        const int row = m0 + wr * 64 + mi * 16 + lhi * 4 + r;
        const int col = n0 + wc * 64 + nj * 16 + llo;
        float v = acc0[mi][nj][r];
        if constexpr (DUAL) v = siluf(v) * acc1[mi][nj][r];
        if constexpr (OUT_BF16) ((__bf16*)Cv)[(size_t)row * N + col] = (__bf16)v;
        else                    ((float*) Cv)[(size_t)row * N + col] = v;
      }
}

// ---------------- product-key retrieval: rank-based top-k, one wave per (token, head) ----
// rank_i = #{j: v_j > v_i} + #{j < i: v_j == v_i}  -> exact lax.top_k (descending, stable).
// All-pairs counts via LDS broadcast reads: independent, pipelined VALU; no shuffle chains.
__global__ __launch_bounds__(256) void retrieval_kernel(
    const float* __restrict__ q,     // [NTOK, QDIM]
    const float* __restrict__ keys,  // [HEADS, NKEYS, 2, 64]
    int* __restrict__ out_idx,       // [NTOK, HEADS, TOPK]
    float* __restrict__ out_prob)    // [NTOK, HEADS, TOPK]
{
  const int token = blockIdx.x;
  const int t = threadIdx.x;
  const int w = t >> 6;  // head
  const int l = t & 63;
  __shared__ float qs [HEADS][2][64];
  __shared__ float sp [HEADS][2][128];
  __shared__ float stv[HEADS][2][8];
  __shared__ int   sti[HEADS][2][8];
  __shared__ float cnd[HEADS][64];

  qs[w][0][l] = q[(size_t)token * QDIM +       w * 64 + l];
  qs[w][1][l] = q[(size_t)token * QDIM + 256 + w * 64 + l];
  __syncthreads();

  // dots: lane handles keys l and l+64 for both p
  const float* kb = keys + ((size_t)(w * NKEYS + l) * 2) * 64;
  const float4* K00 = (const float4*)kb;
  const float4* K01 = (const float4*)(kb + 64);
  const float4* K10 = (const float4*)(kb + 64 * 128);
  const float4* K11 = (const float4*)(kb + 64 * 128 + 64);
  float s00 = 0.f, s01 = 0.f, s10 = 0.f, s11 = 0.f;
#pragma unroll
  for (int n4 = 0; n4 < 16; ++n4) {
    const float4 q0 = *(const float4*)&qs[w][0][n4 * 4];
    const float4 q1 = *(const float4*)&qs[w][1][n4 * 4];
    s00 += dot4(q0, K00[n4]);
    s01 += dot4(q1, K01[n4]);
    s10 += dot4(q0, K10[n4]);
    s11 += dot4(q1, K11[n4]);
  }
  sp[w][0][l] = s00; sp[w][0][64 + l] = s10;
  sp[w][1][l] = s01; sp[w][1][64 + l] = s11;
  __syncthreads();

  // exact ranks of this lane's 4 scores (global key indices: l and 64+l)
  int r00 = 0, r10 = 0, r01 = 0, r11 = 0;
#pragma unroll 16
  for (int j = 0; j < 128; ++j) {
    const float v0 = sp[w][0][j];
    const float v1 = sp[w][1][j];
    r00 += (v0 > s00) || (v0 == s00 && j < l);
    r10 += (v0 > s10) || (v0 == s10 && j < 64 + l);
    r01 += (v1 > s01) || (v1 == s01 && j < l);
    r11 += (v1 > s11) || (v1 == s11 && j < 64 + l);
  }
  if (r00 < TOPK) { stv[w][0][r00] = s00; sti[w][0][r00] = l; }
  if (r10 < TOPK) { stv[w][0][r10] = s10; sti[w][0][r10] = 64 + l; }
  if (r01 < TOPK) { stv[w][1][r01] = s01; sti[w][1][r01] = l; }
  if (r11 < TOPK) { stv[w][1][r11] = s11; sti[w][1][r11] = 64 + l; }
  __syncthreads();

  // combine: lane l = candidate (i=l>>3, j=l&7); flattened position == l (matches ref)
  const int ci = l >> 3, cj = l & 7;
  const float cand = stv[w][0][ci] + stv[w][1][cj];
  const int cid = sti[w][0][ci] * NKEYS + sti[w][1][cj];
  cnd[w][l] = cand;
  __syncthreads();

  int rk = 0;
#pragma unroll 16
  for (int j = 0; j < 64; ++j) {
    const float v = cnd[w][j];
    rk += (v > cand) || (v == cand && j < l);
  }

  // softmax over the top-8 (max over all 64 == max of top-8)
  float mx = cand;
#pragma unroll
  for (int off = 32; off; off >>= 1) mx = fmaxf(mx, __shfl_xor(mx, off));
  const float e = (rk < TOPK) ? __expf(cand - mx) : 0.f;
  float sum = e;
#pragma unroll
  for (int off = 32; off; off >>= 1) sum += __shfl_xor(sum, off);

  if (rk < TOPK) {
    const int o = (token * HEADS + w) * TOPK + rk;
    out_idx [o] = cid;
    out_prob[o] = e / sum;
  }
}

// ---------------- expert mixture: 4 waves x 8 experts, barrier-free inner loop ----------------
__global__ __launch_bounds__(256) void expert_kernel(
    const float* __restrict__ hs,
    const float* __restrict__ down_e,
    const float* __restrict__ up_e,
    const int* __restrict__ idx,
    const float* __restrict__ prob,
    float* __restrict__ out)
{
  const int token = blockIdx.x;
  const int t = threadIdx.x, w = t >> 6, l = t & 63;
  __shared__ float4 sred[4][256];

  const float4* hrow = (const float4*)(hs + (size_t)token * HID);
  const float4 h0 = hrow[l], h1 = hrow[64 + l], h2 = hrow[128 + l], h3 = hrow[192 + l];
  float4 a0 = {0,0,0,0}, a1 = {0,0,0,0}, a2 = {0,0,0,0}, a3 = {0,0,0,0};

  const int*   tidx  = idx  + token * 32 + w * 8;
  const float* tprob = prob + token * 32 + w * 8;
#pragma unroll 2
  for (int e = 0; e < 8; ++e) {
    const int   ex = tidx[e];
    const float p  = tprob[e];
    const float4* drow = (const float4*)(down_e + (size_t)ex * HID);
    const float4 d0 = drow[l], d1 = drow[64 + l], d2 = drow[128 + l], d3 = drow[192 + l];
    float part = dot4(h0, d0) + dot4(h1, d1) + dot4(h2, d2) + dot4(h3, d3);
#pragma unroll
    for (int off = 32; off; off >>= 1) part += __shfl_xor(part, off);
    const float wgt = siluf(part) * p;
    const float4* urow = (const float4*)(up_e + (size_t)ex * HID);
    const float4 u0 = urow[l], u1 = urow[64 + l], u2 = urow[128 + l], u3 = urow[192 + l];
    a0.x += wgt * u0.x; a0.y += wgt * u0.y; a0.z += wgt * u0.z; a0.w += wgt * u0.w;
    a1.x += wgt * u1.x; a1.y += wgt * u1.y; a1.z += wgt * u1.z; a1.w += wgt * u1.w;
    a2.x += wgt * u2.x; a2.y += wgt * u2.y; a2.z += wgt * u2.z; a2.w += wgt * u2.w;
    a3.x += wgt * u3.x; a3.y += wgt * u3.y; a3.z += wgt * u3.z; a3.w += wgt * u3.w;
  }
  sred[w][l] = a0; sred[w][64 + l] = a1; sred[w][128 + l] = a2; sred[w][192 + l] = a3;
  __syncthreads();

  const float4 r0 = sred[0][t], r1 = sred[1][t], r2 = sred[2][t], r3 = sred[3][t];
  float4* o = (float4*)(out + (size_t)token * HID);
  float4 cur = o[t];
  cur.x += r0.x + r1.x + r2.x + r3.x;
  cur.y += r0.y + r1.y + r2.y + r3.y;
  cur.z += r0.z + r1.z + r2.z + r3.z;
  cur.w += r0.w + r1.w + r2.w + r3.w;
  o[t] = cur;
}

extern "C" void kernel_launch(void* const* d_in, const int* in_sizes, int n_in,
                              void* d_out, int out_size, void* d_ws, size_t ws_size,
                              hipStream_t stream)
{
  const float* hs   = (const float*)d_in[0];
  const float* Wq   = (const float*)d_in[1];
  const float* keys = (const float*)d_in[2];
  const float* dwe  = (const float*)d_in[3];
  const float* upe  = (const float*)d_in[4];
  const float* Wg   = (const float*)d_in[5];
  const float* Wu   = (const float*)d_in[6];
  const float* Wd   = (const float*)d_in[7];
  float* out = (float*)d_out;

  float*  qbuf    = (float*)d_ws;
  int*    idxb    = (int*)(qbuf + (size_t)NTOK * QDIM);
  float*  probb   = (float*)(idxb + NTOK * HEADS * TOPK);
  __bf16* hs_bf   = (__bf16*)(probb + NTOK * HEADS * TOPK);
  __bf16* wq_bf   = hs_bf + (size_t)NTOK * HID;
  __bf16* wg_bf   = wq_bf + (size_t)QDIM * HID;
  __bf16* wu_bf   = wg_bf + (size_t)INTERDIM * HID;
  __bf16* wd_bf   = wu_bf + (size_t)INTERDIM * HID;
  __bf16* interbf = wd_bf + (size_t)HID * INTERDIM;

  cast_bf16_kernel<<<4096, 256, 0, stream>>>(hs, hs_bf, NTOK * HID / 4);
  cast_bf16_kernel<<<512,  256, 0, stream>>>(Wq, wq_bf, QDIM * HID / 4);
  cast_bf16_kernel<<<4096, 256, 0, stream>>>(Wg, wg_bf, INTERDIM * HID / 4);
  cast_bf16_kernel<<<4096, 256, 0, stream>>>(Wu, wu_bf, INTERDIM * HID / 4);
  cast_bf16_kernel<<<4096, 256, 0, stream>>>(Wd, wd_bf, HID * INTERDIM / 4);

  gemm_mfma<false, false><<<dim3(QDIM / 128, NTOK / 128), 256, 0, stream>>>(
      hs_bf, wq_bf, nullptr, qbuf, NTOK, QDIM, HID);

  retrieval_kernel<<<NTOK, 256, 0, stream>>>(qbuf, keys, idxb, probb);

  gemm_mfma<true, true><<<dim3(INTERDIM / 128, NTOK / 128), 256, 0, stream>>>(
      hs_bf, wg_bf, wu_bf, interbf, NTOK, INTERDIM, HID);

  gemm_mfma<false, false><<<dim3(HID / 128, NTOK / 128), 256, 0, stream>>>(
      interbf, wd_bf, nullptr, out, NTOK, HID, INTERDIM);

  expert_kernel<<<NTOK, 256, 0, stream>>>(hs, dwe, upe, idxb, probb, out);
}

// Round 5
// 497.760 us; speedup vs baseline: 4.6087x; 1.2648x over previous
//
#include <hip/hip_runtime.h>

#define NTOK 4096
#define HID 1024
#define QDIM 512
#define HEADS 4
#define NKEYS 128
#define TOPK 8
#define INTERDIM 4096

typedef __bf16 bf16x8 __attribute__((ext_vector_type(8)));
typedef __bf16 bf16x4 __attribute__((ext_vector_type(4)));
typedef float f32x4 __attribute__((ext_vector_type(4)));

__device__ __forceinline__ float siluf(float x) { return x / (1.f + __expf(-x)); }
__device__ __forceinline__ float dot4(float4 a, float4 b) {
  return a.x * b.x + a.y * b.y + a.z * b.z + a.w * b.w;
}
// monotone float->u32 map: a > b  <=>  sortable(a) > sortable(b)
__device__ __forceinline__ unsigned sortable(float f) {
  unsigned u = __float_as_uint(f);
  return (u & 0x80000000u) ? ~u : (u | 0x80000000u);
}

#define GLD_LDS16(g, l)                                                                   \
  __builtin_amdgcn_global_load_lds(                                                      \
      (const __attribute__((address_space(1))) unsigned int*)(g),                        \
      (__attribute__((address_space(3))) unsigned int*)(l), 16, 0, 0)

// ---------------- fp32 -> bf16 cast ----------------
__global__ __launch_bounds__(256) void cast_bf16_kernel(const float* __restrict__ in,
                                                        __bf16* __restrict__ out, int n4)
{
  const int stride = gridDim.x * blockDim.x;
  for (int i = blockIdx.x * blockDim.x + threadIdx.x; i < n4; i += stride) {
    const float4 v = ((const float4*)in)[i];
    bf16x4 o;
    o[0] = (__bf16)v.x; o[1] = (__bf16)v.y; o[2] = (__bf16)v.z; o[3] = (__bf16)v.w;
    ((bf16x4*)out)[i] = o;
  }
}

// keys [h][k][p][n] f32 -> kbf [(p*4+h)][k][n] bf16
__global__ __launch_bounds__(256) void cast_keys_kernel(const float* __restrict__ keys,
                                                        __bf16* __restrict__ kbf)
{
  const int i = blockIdx.x * 256 + threadIdx.x;  // 4*128*2*64 = 65536
  const int n = i & 63, p = (i >> 6) & 1, k = (i >> 7) & 127, h = (i >> 14) & 3;
  kbf[(((size_t)(p * 4 + h) * NKEYS) + k) * 64 + n] = (__bf16)keys[i];
}

// ---------------- bf16 MFMA GEMM: C[M,N] = A[M,K] @ B[N,K]^T ----------------
template<bool DUAL, bool OUT_BF16>
__global__ __launch_bounds__(256) void gemm_mfma(
    const __bf16* __restrict__ A, const __bf16* __restrict__ B0,
    const __bf16* __restrict__ B1, void* __restrict__ Cv,
    int M, int N, int K)
{
  __shared__ __attribute__((aligned(16))) __bf16 As [128 * 32];
  __shared__ __attribute__((aligned(16))) __bf16 Bs0[128 * 32];
  __shared__ __attribute__((aligned(16))) __bf16 Bs1[DUAL ? 128 * 32 : 8];

  const int tid  = threadIdx.x;
  const int wave = tid >> 6;
  const int lane = tid & 63;
  const int m0 = blockIdx.y * 128;
  const int n0 = blockIdx.x * 128;
  const int wr = wave >> 1, wc = wave & 1;
  const int lhi = lane >> 4, llo = lane & 15;

  f32x4 acc0[4][4] = {};
  f32x4 acc1[4][4] = {};

  const int c0 = tid, c1 = 256 + tid;
  const int r0 = c0 >> 2, col0 = (c0 & 3) * 8;
  const int r1 = c1 >> 2, col1 = (c1 & 3) * 8;
  __bf16* ldsA0 = &As [(wave * 64) * 8];
  __bf16* ldsA1 = &As [(256 + wave * 64) * 8];
  __bf16* ldsB00 = &Bs0[(wave * 64) * 8];
  __bf16* ldsB01 = &Bs0[(256 + wave * 64) * 8];
  __bf16* ldsB10 = &Bs1[(wave * 64) * 8];
  __bf16* ldsB11 = &Bs1[(256 + wave * 64) * 8];

  for (int k0 = 0; k0 < K; k0 += 32) {
    GLD_LDS16(A  + (size_t)(m0 + r0) * K + k0 + col0, ldsA0);
    GLD_LDS16(A  + (size_t)(m0 + r1) * K + k0 + col1, ldsA1);
    GLD_LDS16(B0 + (size_t)(n0 + r0) * K + k0 + col0, ldsB00);
    GLD_LDS16(B0 + (size_t)(n0 + r1) * K + k0 + col1, ldsB01);
    if constexpr (DUAL) {
      GLD_LDS16(B1 + (size_t)(n0 + r0) * K + k0 + col0, ldsB10);
      GLD_LDS16(B1 + (size_t)(n0 + r1) * K + k0 + col1, ldsB11);
    }
    __syncthreads();

    bf16x8 afr[4], bfr0[4], bfr1[4];
#pragma unroll
    for (int mi = 0; mi < 4; ++mi)
      afr[mi] = *(const bf16x8*)&As[(wr * 64 + mi * 16 + llo) * 32 + lhi * 8];
#pragma unroll
    for (int nj = 0; nj < 4; ++nj)
      bfr0[nj] = *(const bf16x8*)&Bs0[(wc * 64 + nj * 16 + llo) * 32 + lhi * 8];
    if constexpr (DUAL) {
#pragma unroll
      for (int nj = 0; nj < 4; ++nj)
        bfr1[nj] = *(const bf16x8*)&Bs1[(wc * 64 + nj * 16 + llo) * 32 + lhi * 8];
    }
#pragma unroll
    for (int mi = 0; mi < 4; ++mi)
#pragma unroll
      for (int nj = 0; nj < 4; ++nj) {
        acc0[mi][nj] = __builtin_amdgcn_mfma_f32_16x16x32_bf16(afr[mi], bfr0[nj], acc0[mi][nj], 0, 0, 0);
        if constexpr (DUAL)
          acc1[mi][nj] = __builtin_amdgcn_mfma_f32_16x16x32_bf16(afr[mi], bfr1[nj], acc1[mi][nj], 0, 0, 0);
      }
    __syncthreads();
  }

#pragma unroll
  for (int mi = 0; mi < 4; ++mi)
#pragma unroll
    for (int nj = 0; nj < 4; ++nj)
#pragma unroll
      for (int r = 0; r < 4; ++r) {
        const int row = m0 + wr * 64 + mi * 16 + lhi * 4 + r;
        const int col = n0 + wc * 64 + nj * 16 + llo;
        float v = acc0[mi][nj][r];
        if constexpr (DUAL) v = siluf(v) * acc1[mi][nj][r];
        if constexpr (OUT_BF16) ((__bf16*)Cv)[(size_t)row * N + col] = (__bf16)v;
        else                    ((float*) Cv)[(size_t)row * N + col] = v;
      }
}

// ---------------- batched sims GEMM: S[z][tok][key] = Q[tok, off_z:off_z+64] @ Kbf[z]^T ----
// z = p*4+h; M=4096, N=128, K=64; one 128x128 tile per block, grid (32, 8).
__global__ __launch_bounds__(256) void sims_gemm(
    const __bf16* __restrict__ Qbf,  // [4096][512]
    const __bf16* __restrict__ Kbf,  // [8][128][64]
    float* __restrict__ S)           // [8][4096][128]
{
  __shared__ __attribute__((aligned(16))) __bf16 As[128 * 32];
  __shared__ __attribute__((aligned(16))) __bf16 Bs[128 * 32];

  const int z = blockIdx.y;
  const int p = z >> 2, h = z & 3;
  const __bf16* A = Qbf + p * 256 + h * 64;        // lda = 512
  const __bf16* B = Kbf + (size_t)z * NKEYS * 64;  // ldb = 64
  float* C = S + (size_t)z * NTOK * NKEYS;         // ldc = 128

  const int tid  = threadIdx.x;
  const int wave = tid >> 6;
  const int lane = tid & 63;
  const int m0 = blockIdx.x * 128;
  const int wr = wave >> 1, wc = wave & 1;
  const int lhi = lane >> 4, llo = lane & 15;

  f32x4 acc[4][4] = {};

  const int c0 = tid, c1 = 256 + tid;
  const int r0 = c0 >> 2, col0 = (c0 & 3) * 8;
  const int r1 = c1 >> 2, col1 = (c1 & 3) * 8;
  __bf16* ldsA0 = &As[(wave * 64) * 8];
  __bf16* ldsA1 = &As[(256 + wave * 64) * 8];
  __bf16* ldsB0 = &Bs[(wave * 64) * 8];
  __bf16* ldsB1 = &Bs[(256 + wave * 64) * 8];

  for (int k0 = 0; k0 < 64; k0 += 32) {
    GLD_LDS16(A + (size_t)(m0 + r0) * 512 + k0 + col0, ldsA0);
    GLD_LDS16(A + (size_t)(m0 + r1) * 512 + k0 + col1, ldsA1);
    GLD_LDS16(B + (size_t)r0 * 64 + k0 + col0, ldsB0);
    GLD_LDS16(B + (size_t)r1 * 64 + k0 + col1, ldsB1);
    __syncthreads();

    bf16x8 afr[4], bfr[4];
#pragma unroll
    for (int mi = 0; mi < 4; ++mi)
      afr[mi] = *(const bf16x8*)&As[(wr * 64 + mi * 16 + llo) * 32 + lhi * 8];
#pragma unroll
    for (int nj = 0; nj < 4; ++nj)
      bfr[nj] = *(const bf16x8*)&Bs[(wc * 64 + nj * 16 + llo) * 32 + lhi * 8];
#pragma unroll
    for (int mi = 0; mi < 4; ++mi)
#pragma unroll
      for (int nj = 0; nj < 4; ++nj)
        acc[mi][nj] = __builtin_amdgcn_mfma_f32_16x16x32_bf16(afr[mi], bfr[nj], acc[mi][nj], 0, 0, 0);
    __syncthreads();
  }

#pragma unroll
  for (int mi = 0; mi < 4; ++mi)
#pragma unroll
    for (int nj = 0; nj < 4; ++nj)
#pragma unroll
      for (int r = 0; r < 4; ++r) {
        const int row = m0 + wr * 64 + mi * 16 + lhi * 4 + r;
        const int col = wc * 64 + nj * 16 + llo;
        C[(size_t)row * NKEYS + col] = acc[mi][nj][r];
      }
}

// ---------------- topk: 16 tokens x 1 head per block ----------------
// packed u32 = sortable(value) high-bits | (127-j): one unsigned compare == exact
// lax.top_k order (value desc, index asc). Chunk-max prefilter: t0 = min of 8
// chunk-maxes <= 8th-largest, so {v >= t0} contains the top-8.
__global__ __launch_bounds__(256) void topk_kernel(
    const float* __restrict__ S,   // [8][4096][128]  (z = p*4+h)
    int* __restrict__ out_idx,     // [NTOK][HEADS][TOPK]
    float* __restrict__ out_prob)  // [NTOK][HEADS][TOPK]
{
  const int g = blockIdx.x;      // token group
  const int h = blockIdx.y;
  const int t = threadIdx.x;
  const int tok0 = g * 16;

  __shared__ float    sims  [16][2][128];
  __shared__ unsigned packed[16][2][128];
  __shared__ unsigned cmax  [16][2][8];
  __shared__ int      cnt   [16][2];
  __shared__ unsigned char surv[16][2][128];
  __shared__ float    stv   [16][2][8];
  __shared__ unsigned char sti[16][2][8];
  __shared__ unsigned cnd   [16][64];

  // load + pack: thread t -> tok = t>>4, j0 = (t&15)*8, both p
  const int ltok = t >> 4, j0 = (t & 15) * 8;
  unsigned pk[2][8];
#pragma unroll
  for (int p = 0; p < 2; ++p) {
    const float* src = S + (((size_t)(p * 4 + h) * NTOK) + tok0 + ltok) * NKEYS + j0;
    const float4 a = ((const float4*)src)[0];
    const float4 b = ((const float4*)src)[1];
    float v[8] = {a.x, a.y, a.z, a.w, b.x, b.y, b.z, b.w};
#pragma unroll
    for (int e = 0; e < 8; ++e) {
      const unsigned u = (sortable(v[e]) & 0xFFFFFF80u) | (unsigned)(127 - (j0 + e));
      sims  [ltok][p][j0 + e] = v[e];
      packed[ltok][p][j0 + e] = u;
      pk[p][e] = u;
    }
  }
  if (t < 32) cnt[t >> 1][t & 1] = 0;
  __syncthreads();

  // chunk maxes: thread t -> (tok = t>>4, p = (t>>3)&1, c = t&7)
  {
    const int ctok = t >> 4, cp = (t >> 3) & 1, c = t & 7;
    const uint4* q = (const uint4*)&packed[ctok][cp][c * 16];
    unsigned m = 0;
#pragma unroll
    for (int r = 0; r < 4; ++r) {
      const uint4 u = q[r];
      m = max(m, max(max(u.x, u.y), max(u.z, u.w)));
    }
    cmax[ctok][cp][c] = m;
  }
  __syncthreads();

  // survivor test on own 16 values
#pragma unroll
  for (int p = 0; p < 2; ++p) {
    const uint4* cm = (const uint4*)&cmax[ltok][p][0];
    const uint4 ca = cm[0], cb = cm[1];
    const unsigned t0 = min(min(min(ca.x, ca.y), min(ca.z, ca.w)),
                            min(min(cb.x, cb.y), min(cb.z, cb.w)));
#pragma unroll
    for (int e = 0; e < 8; ++e) {
      if (pk[p][e] >= t0) {
        const int s = atomicAdd(&cnt[ltok][p], 1);
        surv[ltok][p][s] = (unsigned char)(j0 + e);
      }
    }
  }
  __syncthreads();

  // exact rank for survivors: 8 threads per (tok,p) group
  {
    const int gid = t >> 3, lane8 = t & 7;
    const int stok = gid >> 1, sp = gid & 1;
    const int n = cnt[stok][sp];
    const uint4* row = (const uint4*)&packed[stok][sp][0];
    for (int s = lane8; s < n; s += 8) {
      const int j = surv[stok][sp][s];
      const unsigned mypk = packed[stok][sp][j];
      int rk = 0;
#pragma unroll 8
      for (int q4 = 0; q4 < 32; ++q4) {
        const uint4 u = row[q4];
        rk += (u.x > mypk) + (u.y > mypk) + (u.z > mypk) + (u.w > mypk);
      }
      if (rk < TOPK) {
        stv[stok][sp][rk] = sims[stok][sp][j];
        sti[stok][sp][rk] = (unsigned char)j;
      }
    }
  }
  __syncthreads();

  // combine + softmax: wave w handles tok = w*4 + round; lane l = candidate l (pos = ci*8+cj)
  const int w = t >> 6, l = t & 63;
  for (int round = 0; round < 4; ++round) {
    const int tok = w * 4 + round;
    const int ci = l >> 3, cj = l & 7;
    const float cv = stv[tok][0][ci] + stv[tok][1][cj];
    const unsigned cpk = (sortable(cv) & 0xFFFFFFC0u) | (unsigned)(63 - l);
    cnd[tok][l] = cpk;
    __syncthreads();
    int rk = 0;
    const uint4* row = (const uint4*)&cnd[tok][0];
#pragma unroll
    for (int q4 = 0; q4 < 16; ++q4) {
      const uint4 u = row[q4];
      rk += (u.x > cpk) + (u.y > cpk) + (u.z > cpk) + (u.w > cpk);
    }
    float mx = cv;
#pragma unroll
    for (int off = 32; off; off >>= 1) mx = fmaxf(mx, __shfl_xor(mx, off));
    const float e = (rk < TOPK) ? __expf(cv - mx) : 0.f;
    float sum = e;
#pragma unroll
    for (int off = 32; off; off >>= 1) sum += __shfl_xor(sum, off);
    if (rk < TOPK) {
      const int o = ((tok0 + tok) * HEADS + h) * TOPK + rk;
      out_idx [o] = (int)sti[tok][0][ci] * NKEYS + (int)sti[tok][1][cj];
      out_prob[o] = e / sum;
    }
  }
}

// ---------------- expert mixture ----------------
__global__ __launch_bounds__(256) void expert_kernel(
    const float* __restrict__ hs,
    const float* __restrict__ down_e,
    const float* __restrict__ up_e,
    const int* __restrict__ idx,
    const float* __restrict__ prob,
    float* __restrict__ out)
{
  const int token = blockIdx.x;
  const int t = threadIdx.x, w = t >> 6, l = t & 63;
  __shared__ float4 sred[4][256];

  const float4* hrow = (const float4*)(hs + (size_t)token * HID);
  const float4 h0 = hrow[l], h1 = hrow[64 + l], h2 = hrow[128 + l], h3 = hrow[192 + l];
  float4 a0 = {0,0,0,0}, a1 = {0,0,0,0}, a2 = {0,0,0,0}, a3 = {0,0,0,0};

  const int*   tidx  = idx  + token * 32 + w * 8;
  const float* tprob = prob + token * 32 + w * 8;
#pragma unroll 2
  for (int e = 0; e < 8; ++e) {
    const int   ex = tidx[e];
    const float p  = tprob[e];
    const float4* drow = (const float4*)(down_e + (size_t)ex * HID);
    const float4 d0 = drow[l], d1 = drow[64 + l], d2 = drow[128 + l], d3 = drow[192 + l];
    float part = dot4(h0, d0) + dot4(h1, d1) + dot4(h2, d2) + dot4(h3, d3);
#pragma unroll
    for (int off = 32; off; off >>= 1) part += __shfl_xor(part, off);
    const float wgt = siluf(part) * p;
    const float4* urow = (const float4*)(up_e + (size_t)ex * HID);
    const float4 u0 = urow[l], u1 = urow[64 + l], u2 = urow[128 + l], u3 = urow[192 + l];
    a0.x += wgt * u0.x; a0.y += wgt * u0.y; a0.z += wgt * u0.z; a0.w += wgt * u0.w;
    a1.x += wgt * u1.x; a1.y += wgt * u1.y; a1.z += wgt * u1.z; a1.w += wgt * u1.w;
    a2.x += wgt * u2.x; a2.y += wgt * u2.y; a2.z += wgt * u2.z; a2.w += wgt * u2.w;
    a3.x += wgt * u3.x; a3.y += wgt * u3.y; a3.z += wgt * u3.z; a3.w += wgt * u3.w;
  }
  sred[w][l] = a0; sred[w][64 + l] = a1; sred[w][128 + l] = a2; sred[w][192 + l] = a3;
  __syncthreads();

  const float4 r0 = sred[0][t], r1 = sred[1][t], r2 = sred[2][t], r3 = sred[3][t];
  float4* o = (float4*)(out + (size_t)token * HID);
  float4 cur = o[t];
  cur.x += r0.x + r1.x + r2.x + r3.x;
  cur.y += r0.y + r1.y + r2.y + r3.y;
  cur.z += r0.z + r1.z + r2.z + r3.z;
  cur.w += r0.w + r1.w + r2.w + r3.w;
  o[t] = cur;
}

extern "C" void kernel_launch(void* const* d_in, const int* in_sizes, int n_in,
                              void* d_out, int out_size, void* d_ws, size_t ws_size,
                              hipStream_t stream)
{
  const float* hs   = (const float*)d_in[0];
  const float* Wq   = (const float*)d_in[1];
  const float* keys = (const float*)d_in[2];
  const float* dwe  = (const float*)d_in[3];
  const float* upe  = (const float*)d_in[4];
  const float* Wg   = (const float*)d_in[5];
  const float* Wu   = (const float*)d_in[6];
  const float* Wd   = (const float*)d_in[7];
  float* out = (float*)d_out;

  __bf16* qbf     = (__bf16*)d_ws;                        // 4096*512 bf16 (4MB)
  __bf16* kbf     = qbf + (size_t)NTOK * QDIM;            // 8*128*64 bf16 (128KB)
  int*    idxb    = (int*)(kbf + 8 * NKEYS * 64);
  float*  probb   = (float*)(idxb + NTOK * HEADS * TOPK);
  __bf16* hs_bf   = (__bf16*)(probb + NTOK * HEADS * TOPK);
  __bf16* wq_bf   = hs_bf + (size_t)NTOK * HID;
  __bf16* wg_bf   = wq_bf + (size_t)QDIM * HID;
  __bf16* wu_bf   = wg_bf + (size_t)INTERDIM * HID;
  __bf16* wd_bf   = wu_bf + (size_t)INTERDIM * HID;
  __bf16* interbf = wd_bf + (size_t)HID * INTERDIM;       // 4096*4096 bf16 (32MB)
  float*  simsb   = (float*)interbf;                      // overlay: 8*4096*128 f32 (16MB), dead before dual-gemm

  cast_bf16_kernel<<<4096, 256, 0, stream>>>(hs, hs_bf, NTOK * HID / 4);
  cast_bf16_kernel<<<512,  256, 0, stream>>>(Wq, wq_bf, QDIM * HID / 4);
  cast_bf16_kernel<<<4096, 256, 0, stream>>>(Wg, wg_bf, INTERDIM * HID / 4);
  cast_bf16_kernel<<<4096, 256, 0, stream>>>(Wu, wu_bf, INTERDIM * HID / 4);
  cast_bf16_kernel<<<4096, 256, 0, stream>>>(Wd, wd_bf, HID * INTERDIM / 4);
  cast_keys_kernel<<<256, 256, 0, stream>>>(keys, kbf);

  // q = hs @ Wq^T  (bf16 out)
  gemm_mfma<false, true><<<dim3(QDIM / 128, NTOK / 128), 256, 0, stream>>>(
      hs_bf, wq_bf, nullptr, qbf, NTOK, QDIM, HID);

  // sims + topk
  sims_gemm<<<dim3(NTOK / 128, 8), 256, 0, stream>>>(qbf, kbf, simsb);
  topk_kernel<<<dim3(NTOK / 16, HEADS), 256, 0, stream>>>(simsb, idxb, probb);

  // inter = silu(hs @ Wg^T) * (hs @ Wu^T)  (bf16 out; overwrites sims region — sims dead)
  gemm_mfma<true, true><<<dim3(INTERDIM / 128, NTOK / 128), 256, 0, stream>>>(
      hs_bf, wg_bf, wu_bf, interbf, NTOK, INTERDIM, HID);

  // out = inter @ Wd^T  (f32 out)
  gemm_mfma<false, false><<<dim3(HID / 128, NTOK / 128), 256, 0, stream>>>(
      interbf, wd_bf, nullptr, out, NTOK, HID, INTERDIM);

  expert_kernel<<<NTOK, 256, 0, stream>>>(hs, dwe, upe, idxb, probb, out);
}

// Round 6
// 356.037 us; speedup vs baseline: 6.4432x; 1.3981x over previous
//
#include <hip/hip_runtime.h>

#define NTOK 4096
#define HID 1024
#define QDIM 512
#define HEADS 4
#define NKEYS 128
#define TOPK 8
#define INTERDIM 4096

typedef __bf16 bf16x8 __attribute__((ext_vector_type(8)));
typedef __bf16 bf16x4 __attribute__((ext_vector_type(4)));
typedef float f32x4 __attribute__((ext_vector_type(4)));

__device__ __forceinline__ float siluf(float x) { return x / (1.f + __expf(-x)); }
__device__ __forceinline__ float dot4(float4 a, float4 b) {
  return a.x * b.x + a.y * b.y + a.z * b.z + a.w * b.w;
}
// monotone float->u32 map: a > b  <=>  sortable(a) > sortable(b)
__device__ __forceinline__ unsigned sortable(float f) {
  unsigned u = __float_as_uint(f);
  return (u & 0x80000000u) ? ~u : (u | 0x80000000u);
}
// bf16 pair in a u32 (little-endian): low half = even elem, high = odd elem
__device__ __forceinline__ float bfl(unsigned u) { return __uint_as_float(u << 16); }
__device__ __forceinline__ float bfh(unsigned u) { return __uint_as_float(u & 0xFFFF0000u); }

#define GLD_LDS16(g, l)                                                                   \
  __builtin_amdgcn_global_load_lds(                                                      \
      (const __attribute__((address_space(1))) unsigned int*)(g),                        \
      (__attribute__((address_space(3))) unsigned int*)(l), 16, 0, 0)

// ---------------- fp32 -> bf16 cast ----------------
__global__ __launch_bounds__(256) void cast_bf16_kernel(const float* __restrict__ in,
                                                        __bf16* __restrict__ out, int n4)
{
  const int stride = gridDim.x * blockDim.x;
  for (int i = blockIdx.x * blockDim.x + threadIdx.x; i < n4; i += stride) {
    const float4 v = ((const float4*)in)[i];
    bf16x4 o;
    o[0] = (__bf16)v.x; o[1] = (__bf16)v.y; o[2] = (__bf16)v.z; o[3] = (__bf16)v.w;
    ((bf16x4*)out)[i] = o;
  }
}

// keys [h][k][p][n] f32 -> kbf [(p*4+h)][k][n] bf16
__global__ __launch_bounds__(256) void cast_keys_kernel(const float* __restrict__ keys,
                                                        __bf16* __restrict__ kbf)
{
  const int i = blockIdx.x * 256 + threadIdx.x;  // 4*128*2*64 = 65536
  const int n = i & 63, p = (i >> 6) & 1, k = (i >> 7) & 127, h = (i >> 14) & 3;
  kbf[(((size_t)(p * 4 + h) * NKEYS) + k) * 64 + n] = (__bf16)keys[i];
}

// ---------------- bf16 MFMA GEMM: C[M,N] = A[M,K] @ B[N,K]^T ----------------
// 512 threads / 8 waves (2 M x 4 N), block tile 128x128, BK=32, wave tile 64x32
// (4x2 fragments of 16x16x32). Dual acc = 64 VGPR -> ~4 waves/SIMD occupancy.
// XCD-aware block swizzle (grid sizes all % 8 == 0).
template<bool DUAL, bool OUT_BF16>
__global__ __launch_bounds__(512) void gemm_mfma(
    const __bf16* __restrict__ A, const __bf16* __restrict__ B0,
    const __bf16* __restrict__ B1, void* __restrict__ Cv,
    int M, int N, int K)
{
  __shared__ __attribute__((aligned(16))) __bf16 As [128 * 32];
  __shared__ __attribute__((aligned(16))) __bf16 Bs0[128 * 32];
  __shared__ __attribute__((aligned(16))) __bf16 Bs1[DUAL ? 128 * 32 : 8];

  // XCD swizzle: contiguous chunk of blocks per XCD
  const int nwg = gridDim.x * gridDim.y;
  int bid = blockIdx.y * gridDim.x + blockIdx.x;
  bid = (bid & 7) * (nwg >> 3) + (bid >> 3);
  const int bx = bid % gridDim.x, by = bid / gridDim.x;

  const int tid  = threadIdx.x;
  const int wave = tid >> 6;
  const int lane = tid & 63;
  const int m0 = by * 128;
  const int n0 = bx * 128;
  const int wr = wave >> 2, wc = wave & 3;       // 2 x 4 wave grid
  const int lhi = lane >> 4, llo = lane & 15;

  f32x4 acc0[4][2] = {};
  f32x4 acc1[4][2] = {};

  // staging: chunk c = tid covers tile row c>>2, cols (c&3)*8 (16B)
  const int r0 = tid >> 2, col0 = (tid & 3) * 8;
  __bf16* ldsA  = &As [(size_t)wave * 512];
  __bf16* ldsB0 = &Bs0[(size_t)wave * 512];
  __bf16* ldsB1 = &Bs1[(size_t)wave * 512];

  for (int k0 = 0; k0 < K; k0 += 32) {
    GLD_LDS16(A  + (size_t)(m0 + r0) * K + k0 + col0, ldsA);
    GLD_LDS16(B0 + (size_t)(n0 + r0) * K + k0 + col0, ldsB0);
    if constexpr (DUAL)
      GLD_LDS16(B1 + (size_t)(n0 + r0) * K + k0 + col0, ldsB1);
    __syncthreads();

    bf16x8 afr[4], bfr0[2], bfr1[2];
#pragma unroll
    for (int mi = 0; mi < 4; ++mi)
      afr[mi] = *(const bf16x8*)&As[(wr * 64 + mi * 16 + llo) * 32 + lhi * 8];
#pragma unroll
    for (int nj = 0; nj < 2; ++nj)
      bfr0[nj] = *(const bf16x8*)&Bs0[(wc * 32 + nj * 16 + llo) * 32 + lhi * 8];
    if constexpr (DUAL) {
#pragma unroll
      for (int nj = 0; nj < 2; ++nj)
        bfr1[nj] = *(const bf16x8*)&Bs1[(wc * 32 + nj * 16 + llo) * 32 + lhi * 8];
    }
#pragma unroll
    for (int mi = 0; mi < 4; ++mi)
#pragma unroll
      for (int nj = 0; nj < 2; ++nj) {
        acc0[mi][nj] = __builtin_amdgcn_mfma_f32_16x16x32_bf16(afr[mi], bfr0[nj], acc0[mi][nj], 0, 0, 0);
        if constexpr (DUAL)
          acc1[mi][nj] = __builtin_amdgcn_mfma_f32_16x16x32_bf16(afr[mi], bfr1[nj], acc1[mi][nj], 0, 0, 0);
      }
    __syncthreads();
  }

#pragma unroll
  for (int mi = 0; mi < 4; ++mi)
#pragma unroll
    for (int nj = 0; nj < 2; ++nj)
#pragma unroll
      for (int r = 0; r < 4; ++r) {
        const int row = m0 + wr * 64 + mi * 16 + lhi * 4 + r;
        const int col = n0 + wc * 32 + nj * 16 + llo;
        float v = acc0[mi][nj][r];
        if constexpr (DUAL) v = siluf(v) * acc1[mi][nj][r];
        if constexpr (OUT_BF16) ((__bf16*)Cv)[(size_t)row * N + col] = (__bf16)v;
        else                    ((float*) Cv)[(size_t)row * N + col] = v;
      }
}

// ---------------- batched sims GEMM: S[z][tok][key] = Q[tok, off_z:off_z+64] @ Kbf[z]^T ----
__global__ __launch_bounds__(256) void sims_gemm(
    const __bf16* __restrict__ Qbf,  // [4096][512]
    const __bf16* __restrict__ Kbf,  // [8][128][64]
    float* __restrict__ S)           // [8][4096][128]
{
  __shared__ __attribute__((aligned(16))) __bf16 As[128 * 32];
  __shared__ __attribute__((aligned(16))) __bf16 Bs[128 * 32];

  const int z = blockIdx.y;
  const int p = z >> 2, h = z & 3;
  const __bf16* A = Qbf + p * 256 + h * 64;        // lda = 512
  const __bf16* B = Kbf + (size_t)z * NKEYS * 64;  // ldb = 64
  float* C = S + (size_t)z * NTOK * NKEYS;         // ldc = 128

  const int tid  = threadIdx.x;
  const int wave = tid >> 6;
  const int lane = tid & 63;
  const int m0 = blockIdx.x * 128;
  const int wr = wave >> 1, wc = wave & 1;
  const int lhi = lane >> 4, llo = lane & 15;

  f32x4 acc[4][4] = {};

  const int c0 = tid, c1 = 256 + tid;
  const int r0 = c0 >> 2, col0 = (c0 & 3) * 8;
  const int r1 = c1 >> 2, col1 = (c1 & 3) * 8;
  __bf16* ldsA0 = &As[(wave * 64) * 8];
  __bf16* ldsA1 = &As[(256 + wave * 64) * 8];
  __bf16* ldsB0 = &Bs[(wave * 64) * 8];
  __bf16* ldsB1 = &Bs[(256 + wave * 64) * 8];

  for (int k0 = 0; k0 < 64; k0 += 32) {
    GLD_LDS16(A + (size_t)(m0 + r0) * 512 + k0 + col0, ldsA0);
    GLD_LDS16(A + (size_t)(m0 + r1) * 512 + k0 + col1, ldsA1);
    GLD_LDS16(B + (size_t)r0 * 64 + k0 + col0, ldsB0);
    GLD_LDS16(B + (size_t)r1 * 64 + k0 + col1, ldsB1);
    __syncthreads();

    bf16x8 afr[4], bfr[4];
#pragma unroll
    for (int mi = 0; mi < 4; ++mi)
      afr[mi] = *(const bf16x8*)&As[(wr * 64 + mi * 16 + llo) * 32 + lhi * 8];
#pragma unroll
    for (int nj = 0; nj < 4; ++nj)
      bfr[nj] = *(const bf16x8*)&Bs[(wc * 64 + nj * 16 + llo) * 32 + lhi * 8];
#pragma unroll
    for (int mi = 0; mi < 4; ++mi)
#pragma unroll
      for (int nj = 0; nj < 4; ++nj)
        acc[mi][nj] = __builtin_amdgcn_mfma_f32_16x16x32_bf16(afr[mi], bfr[nj], acc[mi][nj], 0, 0, 0);
    __syncthreads();
  }

#pragma unroll
  for (int mi = 0; mi < 4; ++mi)
#pragma unroll
    for (int nj = 0; nj < 4; ++nj)
#pragma unroll
      for (int r = 0; r < 4; ++r) {
        const int row = m0 + wr * 64 + mi * 16 + lhi * 4 + r;
        const int col = wc * 64 + nj * 16 + llo;
        C[(size_t)row * NKEYS + col] = acc[mi][nj][r];
      }
}

// ---------------- topk: 16 tokens x 1 head per block ----------------
__global__ __launch_bounds__(256) void topk_kernel(
    const float* __restrict__ S,   // [8][4096][128]  (z = p*4+h)
    int* __restrict__ out_idx,     // [NTOK][HEADS][TOPK]
    float* __restrict__ out_prob)  // [NTOK][HEADS][TOPK]
{
  const int g = blockIdx.x;
  const int h = blockIdx.y;
  const int t = threadIdx.x;
  const int tok0 = g * 16;

  __shared__ float    sims  [16][2][128];
  __shared__ unsigned packed[16][2][128];
  __shared__ unsigned cmax  [16][2][8];
  __shared__ int      cnt   [16][2];
  __shared__ unsigned char surv[16][2][128];
  __shared__ float    stv   [16][2][8];
  __shared__ unsigned char sti[16][2][8];
  __shared__ unsigned cnd   [16][64];

  const int ltok = t >> 4, j0 = (t & 15) * 8;
  unsigned pk[2][8];
#pragma unroll
  for (int p = 0; p < 2; ++p) {
    const float* src = S + (((size_t)(p * 4 + h) * NTOK) + tok0 + ltok) * NKEYS + j0;
    const float4 a = ((const float4*)src)[0];
    const float4 b = ((const float4*)src)[1];
    float v[8] = {a.x, a.y, a.z, a.w, b.x, b.y, b.z, b.w};
#pragma unroll
    for (int e = 0; e < 8; ++e) {
      const unsigned u = (sortable(v[e]) & 0xFFFFFF80u) | (unsigned)(127 - (j0 + e));
      sims  [ltok][p][j0 + e] = v[e];
      packed[ltok][p][j0 + e] = u;
      pk[p][e] = u;
    }
  }
  if (t < 32) cnt[t >> 1][t & 1] = 0;
  __syncthreads();

  {
    const int ctok = t >> 4, cp = (t >> 3) & 1, c = t & 7;
    const uint4* q = (const uint4*)&packed[ctok][cp][c * 16];
    unsigned m = 0;
#pragma unroll
    for (int r = 0; r < 4; ++r) {
      const uint4 u = q[r];
      m = max(m, max(max(u.x, u.y), max(u.z, u.w)));
    }
    cmax[ctok][cp][c] = m;
  }
  __syncthreads();

#pragma unroll
  for (int p = 0; p < 2; ++p) {
    const uint4* cm = (const uint4*)&cmax[ltok][p][0];
    const uint4 ca = cm[0], cb = cm[1];
    const unsigned t0 = min(min(min(ca.x, ca.y), min(ca.z, ca.w)),
                            min(min(cb.x, cb.y), min(cb.z, cb.w)));
#pragma unroll
    for (int e = 0; e < 8; ++e) {
      if (pk[p][e] >= t0) {
        const int s = atomicAdd(&cnt[ltok][p], 1);
        surv[ltok][p][s] = (unsigned char)(j0 + e);
      }
    }
  }
  __syncthreads();

  {
    const int gid = t >> 3, lane8 = t & 7;
    const int stok = gid >> 1, sp = gid & 1;
    const int n = cnt[stok][sp];
    const uint4* row = (const uint4*)&packed[stok][sp][0];
    for (int s = lane8; s < n; s += 8) {
      const int j = surv[stok][sp][s];
      const unsigned mypk = packed[stok][sp][j];
      int rk = 0;
#pragma unroll 8
      for (int q4 = 0; q4 < 32; ++q4) {
        const uint4 u = row[q4];
        rk += (u.x > mypk) + (u.y > mypk) + (u.z > mypk) + (u.w > mypk);
      }
      if (rk < TOPK) {
        stv[stok][sp][rk] = sims[stok][sp][j];
        sti[stok][sp][rk] = (unsigned char)j;
      }
    }
  }
  __syncthreads();

  const int w = t >> 6, l = t & 63;
  for (int round = 0; round < 4; ++round) {
    const int tok = w * 4 + round;
    const int ci = l >> 3, cj = l & 7;
    const float cv = stv[tok][0][ci] + stv[tok][1][cj];
    const unsigned cpk = (sortable(cv) & 0xFFFFFFC0u) | (unsigned)(63 - l);
    cnd[tok][l] = cpk;
    __syncthreads();
    int rk = 0;
    const uint4* row = (const uint4*)&cnd[tok][0];
#pragma unroll
    for (int q4 = 0; q4 < 16; ++q4) {
      const uint4 u = row[q4];
      rk += (u.x > cpk) + (u.y > cpk) + (u.z > cpk) + (u.w > cpk);
    }
    float mx = cv;
#pragma unroll
    for (int off = 32; off; off >>= 1) mx = fmaxf(mx, __shfl_xor(mx, off));
    const float e = (rk < TOPK) ? __expf(cv - mx) : 0.f;
    float sum = e;
#pragma unroll
    for (int off = 32; off; off >>= 1) sum += __shfl_xor(sum, off);
    if (rk < TOPK) {
      const int o = ((tok0 + tok) * HEADS + h) * TOPK + rk;
      out_idx [o] = (int)sti[tok][0][ci] * NKEYS + (int)sti[tok][1][cj];
      out_prob[o] = e / sum;
    }
  }
}

// ---------------- expert mixture (bf16 embeds): 4 waves x 8 experts ----------------
// lane l owns elems [8l..8l+8) and [512+8l..512+8l+8): uint4 = 8 bf16 per load.
__global__ __launch_bounds__(256) void expert_kernel(
    const float* __restrict__ hs,
    const __bf16* __restrict__ down_e,
    const __bf16* __restrict__ up_e,
    const int* __restrict__ idx,
    const float* __restrict__ prob,
    float* __restrict__ out)
{
  const int token = blockIdx.x;
  const int t = threadIdx.x, w = t >> 6, l = t & 63;
  __shared__ float4 sred[4][256];

  const float4* hrow = (const float4*)(hs + (size_t)token * HID);
  const float4 h0 = hrow[2 * l], h1 = hrow[2 * l + 1];
  const float4 h2 = hrow[128 + 2 * l], h3 = hrow[128 + 2 * l + 1];
  float4 a0 = {0,0,0,0}, a1 = {0,0,0,0}, a2 = {0,0,0,0}, a3 = {0,0,0,0};

  const int*   tidx  = idx  + token * 32 + w * 8;
  const float* tprob = prob + token * 32 + w * 8;
#pragma unroll 2
  for (int e = 0; e < 8; ++e) {
    const int   ex = tidx[e];
    const float p  = tprob[e];
    const uint4* dr = (const uint4*)(down_e + (size_t)ex * HID);
    const uint4 dA = dr[l], dB = dr[64 + l];
    float part = h0.x * bfl(dA.x) + h0.y * bfh(dA.x) + h0.z * bfl(dA.y) + h0.w * bfh(dA.y)
               + h1.x * bfl(dA.z) + h1.y * bfh(dA.z) + h1.z * bfl(dA.w) + h1.w * bfh(dA.w)
               + h2.x * bfl(dB.x) + h2.y * bfh(dB.x) + h2.z * bfl(dB.y) + h2.w * bfh(dB.y)
               + h3.x * bfl(dB.z) + h3.y * bfh(dB.z) + h3.z * bfl(dB.w) + h3.w * bfh(dB.w);
#pragma unroll
    for (int off = 32; off; off >>= 1) part += __shfl_xor(part, off);
    const float wgt = siluf(part) * p;
    const uint4* ur = (const uint4*)(up_e + (size_t)ex * HID);
    const uint4 uA = ur[l], uB = ur[64 + l];
    a0.x += wgt * bfl(uA.x); a0.y += wgt * bfh(uA.x); a0.z += wgt * bfl(uA.y); a0.w += wgt * bfh(uA.y);
    a1.x += wgt * bfl(uA.z); a1.y += wgt * bfh(uA.z); a1.z += wgt * bfl(uA.w); a1.w += wgt * bfh(uA.w);
    a2.x += wgt * bfl(uB.x); a2.y += wgt * bfh(uB.x); a2.z += wgt * bfl(uB.y); a2.w += wgt * bfh(uB.y);
    a3.x += wgt * bfl(uB.z); a3.y += wgt * bfh(uB.z); a3.z += wgt * bfl(uB.w); a3.w += wgt * bfh(uB.w);
  }
  sred[w][2 * l] = a0; sred[w][2 * l + 1] = a1;
  sred[w][128 + 2 * l] = a2; sred[w][128 + 2 * l + 1] = a3;
  __syncthreads();

  const float4 r0 = sred[0][t], r1 = sred[1][t], r2 = sred[2][t], r3 = sred[3][t];
  float4* o = (float4*)(out + (size_t)token * HID);
  float4 cur = o[t];
  cur.x += r0.x + r1.x + r2.x + r3.x;
  cur.y += r0.y + r1.y + r2.y + r3.y;
  cur.z += r0.z + r1.z + r2.z + r3.z;
  cur.w += r0.w + r1.w + r2.w + r3.w;
  o[t] = cur;
}

extern "C" void kernel_launch(void* const* d_in, const int* in_sizes, int n_in,
                              void* d_out, int out_size, void* d_ws, size_t ws_size,
                              hipStream_t stream)
{
  const float* hs   = (const float*)d_in[0];
  const float* Wq   = (const float*)d_in[1];
  const float* keys = (const float*)d_in[2];
  const float* dwe  = (const float*)d_in[3];
  const float* upe  = (const float*)d_in[4];
  const float* Wg   = (const float*)d_in[5];
  const float* Wu   = (const float*)d_in[6];
  const float* Wd   = (const float*)d_in[7];
  float* out = (float*)d_out;

  __bf16* qbf     = (__bf16*)d_ws;                        // 4096*512 bf16 (4MB)
  __bf16* kbf     = qbf + (size_t)NTOK * QDIM;            // 8*128*64 bf16 (128KB)
  int*    idxb    = (int*)(kbf + 8 * NKEYS * 64);
  float*  probb   = (float*)(idxb + NTOK * HEADS * TOPK);
  __bf16* hs_bf   = (__bf16*)(probb + NTOK * HEADS * TOPK);
  __bf16* wq_bf   = hs_bf + (size_t)NTOK * HID;
  __bf16* wg_bf   = wq_bf + (size_t)QDIM * HID;
  __bf16* wu_bf   = wg_bf + (size_t)INTERDIM * HID;
  __bf16* wd_bf   = wu_bf + (size_t)INTERDIM * HID;
  __bf16* interbf = wd_bf + (size_t)HID * INTERDIM;       // 4096*4096 bf16 (32MB)
  float*  simsb   = (float*)interbf;                      // overlay, dead before dual-gemm
  // late overlays (regions dead after down-GEMM):
  __bf16* dwe_bf  = interbf;                              // 32MB over interbf
  __bf16* upe_bf  = hs_bf;                                // 32MB over hs..wd (33MB)

  cast_bf16_kernel<<<4096, 256, 0, stream>>>(hs, hs_bf, NTOK * HID / 4);
  cast_bf16_kernel<<<512,  256, 0, stream>>>(Wq, wq_bf, QDIM * HID / 4);
  cast_bf16_kernel<<<4096, 256, 0, stream>>>(Wg, wg_bf, INTERDIM * HID / 4);
  cast_bf16_kernel<<<4096, 256, 0, stream>>>(Wu, wu_bf, INTERDIM * HID / 4);
  cast_bf16_kernel<<<4096, 256, 0, stream>>>(Wd, wd_bf, HID * INTERDIM / 4);
  cast_keys_kernel<<<256, 256, 0, stream>>>(keys, kbf);

  // q = hs @ Wq^T  (bf16 out)
  gemm_mfma<false, true><<<dim3(QDIM / 128, NTOK / 128), 512, 0, stream>>>(
      hs_bf, wq_bf, nullptr, qbf, NTOK, QDIM, HID);

  // sims + topk
  sims_gemm<<<dim3(NTOK / 128, 8), 256, 0, stream>>>(qbf, kbf, simsb);
  topk_kernel<<<dim3(NTOK / 16, HEADS), 256, 0, stream>>>(simsb, idxb, probb);

  // inter = silu(hs @ Wg^T) * (hs @ Wu^T)  (bf16 out; overwrites sims — sims dead)
  gemm_mfma<true, true><<<dim3(INTERDIM / 128, NTOK / 128), 512, 0, stream>>>(
      hs_bf, wg_bf, wu_bf, interbf, NTOK, INTERDIM, HID);

  // out = inter @ Wd^T  (f32 out)
  gemm_mfma<false, false><<<dim3(HID / 128, NTOK / 128), 512, 0, stream>>>(
      interbf, wd_bf, nullptr, out, NTOK, HID, INTERDIM);

  // cast expert embeds into now-dead regions (inter + hs..wd)
  cast_bf16_kernel<<<4096, 256, 0, stream>>>(dwe, dwe_bf, 16384 * HID / 4);
  cast_bf16_kernel<<<4096, 256, 0, stream>>>(upe, upe_bf, 16384 * HID / 4);

  // out += expert mixture
  expert_kernel<<<NTOK, 256, 0, stream>>>(hs, dwe_bf, upe_bf, idxb, probb, out);
}